// Round 11
// baseline (291.147 us; speedup 1.0000x reference)
//
#include <hip/hip_runtime.h>
#include <cstdint>

#define DEVI __device__ __forceinline__

typedef __bf16 bf16;
typedef __bf16 bf16x8 __attribute__((ext_vector_type(8)));
typedef __bf16 bf16x4 __attribute__((ext_vector_type(4)));
typedef __bf16 bf16x2 __attribute__((ext_vector_type(2)));
typedef float floatx4 __attribute__((ext_vector_type(4)));
typedef float f32x2 __attribute__((ext_vector_type(2)));

constexpr int BATCH = 16, SEQ = 2048, DM = 256, DI = 512;
constexpr int M = BATCH * SEQ;   // 32768 rows
constexpr int NC = 64;           // scan chunks per sequence
constexpr int CL = SEQ / NC;     // 32 steps per chunk
constexpr int SC = 8;            // steps per staged sub-chunk (pass1)
constexpr int NSC = CL / SC;     // 4 sub-chunks
static_assert(NC * CL == SEQ, "chunking");
constexpr float LOG2E = 1.4426950408889634f;

// ---- async global->LDS (16B per lane, wave-uniform base + lane*16) ----
DEVI void gl2lds16(const void* g, void* l) {
  __builtin_amdgcn_global_load_lds(
      (const __attribute__((address_space(1))) unsigned int*)(uintptr_t)g,
      (__attribute__((address_space(3))) unsigned int*)(unsigned int)(uintptr_t)l,
      16, 0, 0);
}

DEVI float sigmoidf_(float x) { return 1.f / (1.f + __expf(-x)); }
// native v_exp_f32 (computes 2^x). NOTE: "__exp2f" collides with glibc math.h macros.
DEVI float exp2_(float x) { return __builtin_amdgcn_exp2f(x); }

DEVI float bflo(unsigned u) { return __uint_as_float(u << 16); }
DEVI float bfhi(unsigned u) { return __uint_as_float(u & 0xFFFF0000u); }
DEVI f32x2 sp2(float v) { f32x2 r; r[0] = v; r[1] = v; return r; }

DEVI float softplus_(float s) { return (s > 15.f) ? s : __logf(1.f + __expf(s)); }

// dt for a pair of channels, packed: wp[r] = {dtw[e][r], dtw[e+1][r]}.
// 4 packed accumulators keep the pk_fma chain depth ~4; 16 pk_fma total.
DEVI float2 dt_pair(const float* dr, const f32x2* wp, float2 bias) {
  f32x2 a0, a1, a2, a3;
  a0[0] = bias.x; a0[1] = bias.y;
  a1[0] = 0.f; a1[1] = 0.f;
  a2[0] = 0.f; a2[1] = 0.f;
  a3[0] = 0.f; a3[1] = 0.f;
#pragma unroll
  for (int r = 0; r < 16; r += 4) {
    const float4 v = *(const float4*)(dr + r);
    a0 = a0 + sp2(v.x) * wp[r + 0];
    a1 = a1 + sp2(v.y) * wp[r + 1];
    a2 = a2 + sp2(v.z) * wp[r + 2];
    a3 = a3 + sp2(v.w) * wp[r + 3];
  }
  const f32x2 s = (a0 + a1) + (a2 + a3);
  float2 out;
  out.x = softplus_(s[0]);
  out.y = softplus_(s[1]);
  return out;
}

// round pair to bf16 (so pass1's sdt, stored dt, and pass3's replay all agree)
DEVI float2 rnd2(float2 v) {
  v.x = (float)(bf16)v.x;
  v.y = (float)(bf16)v.y;
  return v;
}

// packed powers: P[s] = d^(s+1), s=0..15 (15 pk_muls, max chain depth 4)
DEVI void powseq(f32x2 d, f32x2* P) {
  P[0] = d;
  P[1] = d * d;
  P[2] = P[1] * d;
  P[3] = P[1] * P[1];
  P[4] = P[3] * d;
  P[5] = P[3] * P[1];
  P[6] = P[3] * P[2];
  P[7] = P[3] * P[3];
  P[8] = P[7] * d;
  P[9] = P[7] * P[1];
  P[10] = P[7] * P[2];
  P[11] = P[7] * P[3];
  P[12] = P[7] * P[4];
  P[13] = P[7] * P[5];
  P[14] = P[7] * P[6];
  P[15] = P[7] * P[7];
}

// ---- bulk stager: 8 rows x 512 e (bf16) into LDS, 512 chunks of 16B ----
DEVI void stage_rows(const bf16* src, bf16* dst, int tid) {
  gl2lds16((const char*)src + tid * 16, (char*)dst + tid * 16);
  gl2lds16((const char*)src + tid * 16 + 4096, (char*)dst + tid * 16 + 4096);
}

// =================== prep: weights fp32 -> bf16, A2 = -exp(A_log)*log2e, power-law flag ===================
__global__ __launch_bounds__(256) void prep_kernel(
    const float* __restrict__ w1, const float* __restrict__ wx,
    const float* __restrict__ wo, const float* __restrict__ alog,
    bf16* __restrict__ w1b, bf16* __restrict__ wxb, bf16* __restrict__ wob,
    float* __restrict__ An, int* __restrict__ flags) {
  constexpr int n1 = 1024 * 256, n2 = 48 * 512, n3 = 256 * 512;
  int i = blockIdx.x * 256 + threadIdx.x;
  if (i < n1) w1b[i] = (bf16)w1[i];
  else if (i < n1 + n2) wxb[i - n1] = (bf16)wx[i - n1];
  else if (i < n1 + n2 + n3) wob[i - n1 - n2] = (bf16)wo[i - n1 - n2];
  else if (i < n1 + n2 + n3 + DI) {
    const int e = i - (n1 + n2 + n3);
    const float a0 = -__expf(alog[e * 16]);
    bool ok = (a0 < 0.f);
#pragma unroll 1
    for (int s = 0; s < 16; s++) {
      const float a = -__expf(alog[e * 16 + s]);
      An[e * 16 + s] = a * LOG2E;
      ok = ok && (__builtin_fabsf(a / a0 - (float)(s + 1)) < 1e-3f);
    }
    flags[e] = ok ? 1 : 0;
  }
}

// =================== LayerNorm: one wave per 256-col row, bf16 out ===================
__global__ __launch_bounds__(256) void ln_kernel(
    const float* __restrict__ x, const float* __restrict__ w,
    const float* __restrict__ b, bf16* __restrict__ xn) {
  const int row = blockIdx.x * 4 + (threadIdx.x >> 6);
  const int lane = threadIdx.x & 63;
  const float4 v = ((const float4*)(x + (size_t)row * DM))[lane];
  float s = v.x + v.y + v.z + v.w;
  float s2 = v.x * v.x + v.y * v.y + v.z * v.z + v.w * v.w;
#pragma unroll
  for (int m = 1; m < 64; m <<= 1) { s += __shfl_xor(s, m); s2 += __shfl_xor(s2, m); }
  const float mu = s * (1.f / DM);
  const float var = s2 * (1.f / DM) - mu * mu;
  const float rs = rsqrtf(var + 1e-5f);
  const float4 wv = ((const float4*)w)[lane];
  const float4 bv = ((const float4*)b)[lane];
  bf16x4 o;
  o[0] = (bf16)((v.x - mu) * rs * wv.x + bv.x);
  o[1] = (bf16)((v.y - mu) * rs * wv.y + bv.y);
  o[2] = (bf16)((v.z - mu) * rs * wv.z + bv.z);
  o[3] = (bf16)((v.w - mu) * rs * wv.w + bv.w);
  *(bf16x4*)(xn + (size_t)row * DM + lane * 4) = o;
}

// =================== NT bf16 GEMM: C[M,N] = A[M,K] * W[N,K]^T (m97 structure) ===================
// XCD-aware 1-D grid: xcd = id&7 owns contiguous M/8 slice (A L2-resident per XCD),
// iterates all N-tiles (W <=512KB, L2-resident). Cuts A re-reads from NB x to ~1x.
template <int N, int K, bool OUT_BF16, bool RESID>
__global__ __launch_bounds__(256) void gemm_nt(const bf16* __restrict__ A,
                                               const bf16* __restrict__ W,
                                               void* __restrict__ out,
                                               const float* __restrict__ resid) {
  constexpr int BK = 32;
  constexpr int NB = N / 128;
  constexpr int MT_PER = (M / 128) / 8;  // M-tiles per XCD
  __shared__ __align__(16) bf16 lA[128 * BK];
  __shared__ __align__(16) bf16 lB[128 * BK];
  const int tid = threadIdx.x;
  const int id = blockIdx.x;
  const int xcd = id & 7;
  const int local = id >> 3;
  const int bm = (xcd * MT_PER + local / NB) * 128;
  const int bn = (local % NB) * 128;
  const int wave = tid >> 6, lane = tid & 63;
  const int wm = (wave >> 1) * 64, wn = (wave & 1) * 64;
  const int q = lane >> 4, r = lane & 15;
  floatx4 acc[4][4] = {};
  const int c0 = wave * 64 + lane;
  const int row0 = c0 >> 2, kp = (c0 & 3) * 8;
  for (int k0 = 0; k0 < K; k0 += BK) {
    gl2lds16(A + (size_t)(bm + row0) * K + k0 + kp, lA + c0 * 8);
    gl2lds16(A + (size_t)(bm + row0 + 64) * K + k0 + kp, lA + (c0 + 256) * 8);
    gl2lds16(W + (size_t)(bn + row0) * K + k0 + kp, lB + c0 * 8);
    gl2lds16(W + (size_t)(bn + row0 + 64) * K + k0 + kp, lB + (c0 + 256) * 8);
    __syncthreads();
    bf16x8 af[4], bfr[4];
#pragma unroll
    for (int i = 0; i < 4; i++) af[i] = *(const bf16x8*)&lA[(wm + i * 16 + r) * BK + q * 8];
#pragma unroll
    for (int j = 0; j < 4; j++) bfr[j] = *(const bf16x8*)&lB[(wn + j * 16 + r) * BK + q * 8];
#pragma unroll
    for (int i = 0; i < 4; i++)
#pragma unroll
      for (int j = 0; j < 4; j++)
        acc[i][j] = __builtin_amdgcn_mfma_f32_16x16x32_bf16(af[i], bfr[j], acc[i][j], 0, 0, 0);
    __syncthreads();
  }
#pragma unroll
  for (int i = 0; i < 4; i++)
#pragma unroll
    for (int j = 0; j < 4; j++)
#pragma unroll
      for (int t = 0; t < 4; t++) {
        const int row = bm + wm + i * 16 + q * 4 + t;
        const int col = bn + wn + j * 16 + r;
        const size_t idx = (size_t)row * N + col;
        float v = acc[i][j][t];
        if constexpr (OUT_BF16) {
          ((bf16*)out)[idx] = (bf16)v;
        } else {
          if constexpr (RESID) v += resid[idx];
          ((float*)out)[idx] = v;
        }
      }
}

// =================== causal depthwise conv(4) + SiLU ===================
// thread = 2 adjacent e (packed 4B coalesced loads), 8 positions/thread.
__global__ __launch_bounds__(256) void conv_silu(const bf16* __restrict__ xz,
                                                 const float* __restrict__ cw,
                                                 const float* __restrict__ cb,
                                                 bf16* __restrict__ xc) {
  const int tid = threadIdx.x;
  const int e2 = tid * 2;              // [0,512) in steps of 2
  const int p0 = blockIdx.x * 8;
  const int b = blockIdx.y;
  const float4 w0 = ((const float4*)cw)[e2];
  const float4 w1 = ((const float4*)cw)[e2 + 1];
  const float2 bias = *(const float2*)(cb + e2);
  float xa[11], xb_[11];
#pragma unroll
  for (int j = 0; j < 11; j++) {
    const int pos = p0 - 3 + j;
    float fa = 0.f, fb = 0.f;
    if (pos >= 0) {  // block-uniform (only blockIdx.x==0 has pos<0)
      const unsigned u = *(const unsigned*)(xz + ((size_t)b * SEQ + pos) * 1024 + e2);
      fa = __uint_as_float(u << 16);
      fb = __uint_as_float(u & 0xFFFF0000u);
    }
    xa[j] = fa; xb_[j] = fb;
  }
#pragma unroll
  for (int k = 0; k < 8; k++) {
    const float a0 = bias.x + xa[k] * w0.x + xa[k + 1] * w0.y + xa[k + 2] * w0.z + xa[k + 3] * w0.w;
    const float a1 = bias.y + xb_[k] * w1.x + xb_[k + 1] * w1.y + xb_[k + 2] * w1.z + xb_[k + 3] * w1.w;
    bf16x2 o;
    o[0] = (bf16)(a0 * sigmoidf_(a0));
    o[1] = (bf16)(a1 * sigmoidf_(a1));
    *(bf16x2*)(xc + ((size_t)b * SEQ + p0 + k) * DI + e2) = o;
  }
}

// =================== x_proj: dbc[M,48] = xc[M,512] * Wx[48,512]^T ===================
// 64-row tiles (512 blocks), wave = 16 rows x 48 cols.
__global__ __launch_bounds__(256) void gemm_xproj(const bf16* __restrict__ A,
                                                  const bf16* __restrict__ W,
                                                  float* __restrict__ out) {
  constexpr int K = DI;
  __shared__ __align__(16) bf16 lW[48 * K];   // 49152 B
  __shared__ __align__(16) bf16 lA[64 * 32];  // 4096 B
  const int tid = threadIdx.x;
  const int wave = tid >> 6, lane = tid & 63;
  const int bm = blockIdx.x * 64;
  const int q = lane >> 4, r = lane & 15;
#pragma unroll
  for (int rd = 0; rd < 12; rd++) {  // 3072 chunks of 16B
    const int c = rd * 256 + tid;
    gl2lds16((const char*)W + (size_t)c * 16, (char*)lW + (size_t)c * 16);
  }
  const int row0 = tid >> 2, kp = (tid & 3) * 8;
  const int wm = wave * 16;
  floatx4 acc[3] = {};
  for (int k0 = 0; k0 < K; k0 += 32) {
    gl2lds16(A + (size_t)(bm + row0) * K + k0 + kp, lA + tid * 8);
    __syncthreads();
    bf16x8 af = *(const bf16x8*)&lA[(wm + r) * 32 + q * 8];
#pragma unroll
    for (int j = 0; j < 3; j++) {
      const bf16x8 bfr = *(const bf16x8*)&lW[(j * 16 + r) * K + k0 + q * 8];
      acc[j] = __builtin_amdgcn_mfma_f32_16x16x32_bf16(af, bfr, acc[j], 0, 0, 0);
    }
    __syncthreads();
  }
#pragma unroll
  for (int j = 0; j < 3; j++)
#pragma unroll
    for (int t = 0; t < 4; t++)
      out[(size_t)(bm + wm + q * 4 + t) * 48 + j * 16 + r] = acc[j][t];
}

// =================== scan pass1: per-chunk aggregates (dt fused + STORED) ===================
// 2 adjacent e per thread; xc bulk-staged (dbuf); dbc[:,0:32] staged once;
// dt = softplus(dbc[:,0:16] . dtw[e] + bias) via packed-pair FMA, rounded to
// bf16 (consistent with pass3's replay), stored to dtout for pass3 to reuse.
// Slow path reads An through a volatile pointer (never taken in practice;
// keeps its 32 A-values out of the static VGPR allocation).
__global__ __launch_bounds__(256) void scan_pass1(const bf16* __restrict__ xc,
                                                  const float* __restrict__ dbc,
                                                  const float* __restrict__ An,
                                                  const int* __restrict__ flags,
                                                  const float* __restrict__ dtw,
                                                  const float* __restrict__ dtb,
                                                  bf16* __restrict__ dtout,
                                                  float* __restrict__ U,
                                                  float* __restrict__ SD) {
  __shared__ __align__(16) float sbc[CL * 32];          // 4 KB: per pos dtr[16] B[16]
  __shared__ __align__(16) bf16 sxc_[2][SC * DI];       // 2 x 8 KB
  const int tid = threadIdx.x;
  const int e2 = tid * 2;
  const int ch = blockIdx.x, b = blockIdx.y;
  const size_t posBase = (size_t)b * SEQ + (size_t)ch * CL;
  {  // stage dbc cols 0..32 of CL rows: 256 chunks of 16B (all threads)
    const int il = tid >> 3, f = (tid & 7) * 4;
    gl2lds16(dbc + (posBase + il) * 48 + f, (char*)sbc + tid * 16);
  }
  stage_rows(xc + posBase * DI, sxc_[0], tid);
  const int2 fl = *(const int2*)(flags + e2);
  const int fast = fl.x & fl.y;
  f32x2 h[16];
#pragma unroll
  for (int s = 0; s < 16; s++) { h[s][0] = 0.f; h[s][1] = 0.f; }
  f32x2 sdt2; sdt2[0] = 0.f; sdt2[1] = 0.f;
  f32x2 A02; A02[0] = An[(size_t)e2 * 16]; A02[1] = An[(size_t)e2 * 16 + 16];
  // dt weights as packed pairs wp[r] = {dtw[e2][r], dtw[e2+1][r]}
  f32x2 wp[16];
#pragma unroll
  for (int r = 0; r < 16; r += 4) {
    float4 t0 = *(const float4*)(dtw + (size_t)e2 * 16 + r);
    float4 t1 = *(const float4*)(dtw + (size_t)(e2 + 1) * 16 + r);
    wp[r + 0][0] = t0.x; wp[r + 0][1] = t1.x;
    wp[r + 1][0] = t0.y; wp[r + 1][1] = t1.y;
    wp[r + 2][0] = t0.z; wp[r + 2][1] = t1.z;
    wp[r + 3][0] = t0.w; wp[r + 3][1] = t1.w;
  }
  const float2 bias = *(const float2*)(dtb + e2);
  __syncthreads();
  float2 dtc = rnd2(dt_pair(sbc, wp, bias));  // dt for step 0 (bf16-rounded)
#pragma unroll 1
  for (int sc = 0; sc < NSC; sc++) {
    const int cb = sc & 1;
    if (sc + 1 < NSC)
      stage_rows(xc + (posBase + (sc + 1) * SC) * DI, sxc_[cb ^ 1], tid);
    const char* sxcb = (const char*)sxc_[cb];
    const int tid4 = tid * 4;
    if (fast) {
#pragma unroll 2
      for (int il = 0; il < SC; il++) {
        const int ig = sc * SC + il;
        const int ng = (ig + 1 < CL) ? (ig + 1) : ig;
        const float2 dtn = rnd2(dt_pair(sbc + ng * 32, wp, bias));
        const unsigned ux = *(const unsigned*)(sxcb + il * 1024 + tid4);
        bf16x2 dto; dto[0] = (bf16)dtc.x; dto[1] = (bf16)dtc.y;
        *(bf16x2*)(dtout + (posBase + ig) * DI + e2) = dto;
        f32x2 dt2; dt2[0] = dtc.x; dt2[1] = dtc.y;
        f32x2 xv2; xv2[0] = bflo(ux); xv2[1] = bfhi(ux);
        const f32x2 dtx2 = dt2 * xv2;
        sdt2 = sdt2 + dt2;
        const f32x2 t = dt2 * A02;
        f32x2 d; d[0] = exp2_(t[0]); d[1] = exp2_(t[1]);
        f32x2 P[16];
        powseq(d, P);
        const float4* bb = (const float4*)(sbc + ig * 32 + 16);
#pragma unroll
        for (int g = 0; g < 4; g++) {
          const float4 B4 = bb[g];
          h[4 * g + 0] = P[4 * g + 0] * h[4 * g + 0] + dtx2 * sp2(B4.x);
          h[4 * g + 1] = P[4 * g + 1] * h[4 * g + 1] + dtx2 * sp2(B4.y);
          h[4 * g + 2] = P[4 * g + 2] * h[4 * g + 2] + dtx2 * sp2(B4.z);
          h[4 * g + 3] = P[4 * g + 3] * h[4 * g + 3] + dtx2 * sp2(B4.w);
        }
        dtc = dtn;
      }
    } else {
      // cold path (flags pattern broken): A read via volatile to avoid
      // register promotion; correctness identical.
      const volatile float* Ap = An + (size_t)e2 * 16;
      const volatile float* Bp = An + (size_t)e2 * 16 + 16;
#pragma unroll 1
      for (int il = 0; il < SC; il++) {
        const int ig = sc * SC + il;
        const int ng = (ig + 1 < CL) ? (ig + 1) : ig;
        const float2 dtn = rnd2(dt_pair(sbc + ng * 32, wp, bias));
        const unsigned ux = *(const unsigned*)(sxcb + il * 1024 + tid4);
        bf16x2 dto; dto[0] = (bf16)dtc.x; dto[1] = (bf16)dtc.y;
        *(bf16x2*)(dtout + (posBase + ig) * DI + e2) = dto;
        const float dta = dtc.x, dtb_v = dtc.y;
        const float xa = bflo(ux), xb = bfhi(ux);
        const float dtxa = dta * xa, dtxb = dtb_v * xb;
        sdt2[0] += dta; sdt2[1] += dtb_v;
        const float* bc = sbc + ig * 32 + 16;
#pragma unroll 1
        for (int s = 0; s < 16; s++) {
          const float bv = bc[s];
          h[s][0] = exp2_(dta * Ap[s]) * h[s][0] + dtxa * bv;
          h[s][1] = exp2_(dtb_v * Bp[s]) * h[s][1] + dtxb * bv;
        }
        dtc = dtn;
      }
    }
    __syncthreads();  // drain staging + protect buffer reuse
  }
  float* up = U + ((size_t)(b * NC + ch) * DI + e2) * 16;
#pragma unroll
  for (int i = 0; i < 4; i++) {
    float4 o; o.x = h[4 * i][0]; o.y = h[4 * i + 1][0]; o.z = h[4 * i + 2][0]; o.w = h[4 * i + 3][0];
    ((float4*)up)[i] = o;
  }
#pragma unroll
  for (int i = 0; i < 4; i++) {
    float4 o; o.x = h[4 * i][1]; o.y = h[4 * i + 1][1]; o.z = h[4 * i + 2][1]; o.w = h[4 * i + 3][1];
    ((float4*)up)[4 + i] = o;
  }
  float2 sdo; sdo.x = sdt2[0]; sdo.y = sdt2[1];
  *(float2*)(SD + (size_t)(b * NC + ch) * DI + e2) = sdo;
}

// =================== scan pass2: combine chunk aggregates, parallel over (b,e,s) ===================
// group-of-16 pipelined loads (32 loads in flight while computing previous group).
__global__ __launch_bounds__(256) void scan_pass2(const float* __restrict__ SD,
                                                  float* U,
                                                  const float* __restrict__ An) {
  const int t = blockIdx.x * 256 + threadIdx.x;  // over BATCH*DI*16
  const int s = t & 15;
  const int e = (t >> 4) & (DI - 1);
  const int b = t >> 13;
  const float Av = An[e * 16 + s];  // pre-scaled by log2e
  const float* sdp = SD + (size_t)b * NC * DI + e;
  float* up = U + ((size_t)b * NC * DI + e) * 16 + s;
  float sA_[16], uA_[16], sB_[16], uB_[16];
#pragma unroll
  for (int j = 0; j < 16; j++) {
    sA_[j] = sdp[(size_t)j * DI];
    uA_[j] = up[(size_t)j * DI * 16];
  }
  float h = 0.f;
#pragma unroll 1
  for (int c0 = 0; c0 < NC; c0 += 32) {
#pragma unroll
    for (int j = 0; j < 16; j++) {
      sB_[j] = sdp[(size_t)(c0 + 16 + j) * DI];
      uB_[j] = up[(size_t)(c0 + 16 + j) * DI * 16];
    }
#pragma unroll
    for (int j = 0; j < 16; j++) {
      const float h0 = h;
      h = exp2_(Av * sA_[j]) * h0 + uA_[j];
      up[(size_t)(c0 + j) * DI * 16] = h0;
    }
    const int nn = (c0 + 32 < NC) ? (c0 + 32) : (NC - 16);
#pragma unroll
    for (int j = 0; j < 16; j++) {
      sA_[j] = sdp[(size_t)(nn + j) * DI];
      uA_[j] = up[(size_t)(nn + j) * DI * 16];
    }
#pragma unroll
    for (int j = 0; j < 16; j++) {
      const float h0 = h;
      h = exp2_(Av * sB_[j]) * h0 + uB_[j];
      up[(size_t)(c0 + 16 + j) * DI * 16] = h0;
    }
  }
}

// =================== scan pass3: replay chunk from true h0, emit gated y ===================
// 2 adjacent e per thread; software-pipelined global loads (prefetch il+1).
// dt read from pass1's stored buffer; slow-path A via volatile (VGPR trim).
__global__ __launch_bounds__(256) void scan_pass3(const bf16* __restrict__ dt,
                                                  const bf16* __restrict__ xc,
                                                  const bf16* __restrict__ xz,
                                                  const float* __restrict__ dbc,
                                                  const float* __restrict__ An,
                                                  const int* __restrict__ flags,
                                                  const float* __restrict__ H0,
                                                  const float* __restrict__ Dp,
                                                  bf16* __restrict__ yg) {
  __shared__ __align__(16) float sbc[CL * 32];  // per pos: B[16] C[16]
  const int tid = threadIdx.x;
  const int e2 = tid * 2;
  const int ch = blockIdx.x, b = blockIdx.y;
  const size_t posBase = (size_t)b * SEQ + (size_t)ch * CL;
  {
    const int il = tid >> 3, f = (tid & 7) * 4;
    gl2lds16(dbc + (posBase + il) * 48 + 16 + f, (char*)sbc + tid * 16);
  }
  const int2 fl = *(const int2*)(flags + e2);
  const int fast = fl.x & fl.y;
  f32x2 h[16];
  const float* hp = H0 + ((size_t)(b * NC + ch) * DI + e2) * 16;
#pragma unroll
  for (int i = 0; i < 4; i++) {
    const float4 h4 = ((const float4*)hp)[i];
    h[4 * i][0] = h4.x; h[4 * i + 1][0] = h4.y; h[4 * i + 2][0] = h4.z; h[4 * i + 3][0] = h4.w;
  }
#pragma unroll
  for (int i = 0; i < 4; i++) {
    const float4 h4 = ((const float4*)hp)[4 + i];
    h[4 * i][1] = h4.x; h[4 * i + 1][1] = h4.y; h[4 * i + 2][1] = h4.z; h[4 * i + 3][1] = h4.w;
  }
  const float2 Dv = *(const float2*)(Dp + e2);
  f32x2 Dv2; Dv2[0] = Dv.x; Dv2[1] = Dv.y;
  f32x2 A02; A02[0] = An[(size_t)e2 * 16]; A02[1] = An[(size_t)e2 * 16 + 16];
  // prefetch il=0
  const char* pdt = (const char*)(dt + posBase * DI + e2);
  const char* pxc = (const char*)(xc + posBase * DI + e2);
  const char* pxz = (const char*)(xz + posBase * 1024 + DI + e2);
  unsigned ud = *(const unsigned*)pdt;
  unsigned ux = *(const unsigned*)pxc;
  unsigned uz = *(const unsigned*)pxz;
  __syncthreads();
  if (fast) {
#pragma unroll 1
    for (int il = 0; il < CL; il++) {
      const int np = (il + 1 < CL) ? (il + 1) : il;
      const unsigned nud = *(const unsigned*)(pdt + (size_t)np * DI * 2);
      const unsigned nux = *(const unsigned*)(pxc + (size_t)np * DI * 2);
      const unsigned nuz = *(const unsigned*)(pxz + (size_t)np * 1024 * 2);
      const size_t pos = posBase + il;
      f32x2 dt2; dt2[0] = bflo(ud); dt2[1] = bfhi(ud);
      f32x2 xv2; xv2[0] = bflo(ux); xv2[1] = bfhi(ux);
      f32x2 z2; z2[0] = bflo(uz); z2[1] = bfhi(uz);
      const f32x2 dtx2 = dt2 * xv2;
      const f32x2 t = dt2 * A02;
      f32x2 d; d[0] = exp2_(t[0]); d[1] = exp2_(t[1]);
      f32x2 P[16];
      powseq(d, P);
      const float4* bb = (const float4*)(sbc + il * 32);
      f32x2 Yv[4];
#pragma unroll
      for (int g = 0; g < 4; g++) { Yv[g][0] = 0.f; Yv[g][1] = 0.f; }
#pragma unroll
      for (int g = 0; g < 4; g++) {
        const float4 B4 = bb[g];
        const float4 C4 = bb[4 + g];
        h[4 * g + 0] = P[4 * g + 0] * h[4 * g + 0] + dtx2 * sp2(B4.x);
        Yv[g] = Yv[g] + h[4 * g + 0] * sp2(C4.x);
        h[4 * g + 1] = P[4 * g + 1] * h[4 * g + 1] + dtx2 * sp2(B4.y);
        Yv[g] = Yv[g] + h[4 * g + 1] * sp2(C4.y);
        h[4 * g + 2] = P[4 * g + 2] * h[4 * g + 2] + dtx2 * sp2(B4.z);
        Yv[g] = Yv[g] + h[4 * g + 2] * sp2(C4.z);
        h[4 * g + 3] = P[4 * g + 3] * h[4 * g + 3] + dtx2 * sp2(B4.w);
        Yv[g] = Yv[g] + h[4 * g + 3] * sp2(C4.w);
      }
      const f32x2 Ys = (Yv[0] + Yv[1]) + (Yv[2] + Yv[3]);
      f32x2 gz; gz[0] = z2[0] * sigmoidf_(z2[0]); gz[1] = z2[1] * sigmoidf_(z2[1]);
      const f32x2 yv2 = (Ys + Dv2 * xv2) * gz;
      bf16x2 o; o[0] = (bf16)yv2[0]; o[1] = (bf16)yv2[1];
      *(bf16x2*)(yg + pos * DI + e2) = o;
      ud = nud; ux = nux; uz = nuz;
    }
  } else {
    // cold path: A via volatile (keeps 32 A-values out of static VGPR count)
    const volatile float* Ap = An + (size_t)e2 * 16;
    const volatile float* Bp = An + (size_t)e2 * 16 + 16;
#pragma unroll 1
    for (int il = 0; il < CL; il++) {
      const int np = (il + 1 < CL) ? (il + 1) : il;
      const unsigned nud = *(const unsigned*)(pdt + (size_t)np * DI * 2);
      const unsigned nux = *(const unsigned*)(pxc + (size_t)np * DI * 2);
      const unsigned nuz = *(const unsigned*)(pxz + (size_t)np * 1024 * 2);
      const size_t pos = posBase + il;
      const float dta = bflo(ud), dtb_v = bfhi(ud);
      const float xa = bflo(ux), xb = bfhi(ux);
      const float za = bflo(uz), zb = bfhi(uz);
      const float dtxa = dta * xa, dtxb = dtb_v * xb;
      const float* bc = sbc + il * 32;
      float ya = 0.f, yb = 0.f;
#pragma unroll 1
      for (int s = 0; s < 16; s++) {
        const float bv = bc[s], cv = bc[16 + s];
        const float ha = exp2_(dta * Ap[s]) * h[s][0] + dtxa * bv;
        const float hb = exp2_(dtb_v * Bp[s]) * h[s][1] + dtxb * bv;
        h[s][0] = ha; h[s][1] = hb;
        ya += ha * cv; yb += hb * cv;
      }
      const float yva = (ya + Dv.x * xa) * za * sigmoidf_(za);
      const float yvb = (yb + Dv.y * xb) * zb * sigmoidf_(zb);
      bf16x2 o; o[0] = (bf16)yva; o[1] = (bf16)yvb;
      *(bf16x2*)(yg + pos * DI + e2) = o;
      ud = nud; ux = nux; uz = nuz;
    }
  }
}

// =================== host ===================
extern "C" void kernel_launch(void* const* d_in, const int* in_sizes, int n_in,
                              void* d_out, int out_size, void* d_ws, size_t ws_size,
                              hipStream_t stream) {
  const float* x = (const float*)d_in[0];
  const float* ln_w = (const float*)d_in[1];
  const float* ln_b = (const float*)d_in[2];
  const float* w_in = (const float*)d_in[3];
  const float* conv_w = (const float*)d_in[4];
  const float* conv_b = (const float*)d_in[5];
  const float* w_x = (const float*)d_in[6];
  const float* w_dt = (const float*)d_in[7];
  const float* b_dt = (const float*)d_in[8];
  const float* a_log = (const float*)d_in[9];
  const float* d_par = (const float*)d_in[10];
  const float* w_out = (const float*)d_in[11];

  char* ws = (char*)d_ws;
  size_t off = 0;
  auto alloc = [&](size_t bytes) {
    void* p = ws + off;
    off = (off + bytes + 255) & ~(size_t)255;
    return p;
  };
  bf16* xzb = (bf16*)alloc((size_t)M * 1024 * 2);
  bf16* xcb = (bf16*)alloc((size_t)M * DI * 2);
  float* dbc = (float*)alloc((size_t)M * 48 * 4);
  bf16* dtb_ = (bf16*)alloc((size_t)M * DI * 2);
  bf16* ygb = (bf16*)alloc((size_t)M * DI * 2);
  float* U = (float*)alloc((size_t)BATCH * NC * DI * 16 * 4);  // 33.5 MB
  bf16* xn = (bf16*)U;  // alias: xn dead before U's first write (pass1 after gemm#1)
  float* SD = (float*)alloc((size_t)BATCH * NC * DI * 4);      // 2.1 MB
  bf16* w1b = (bf16*)alloc(1024 * 256 * 2);
  bf16* wxb = (bf16*)alloc(48 * 512 * 2);
  bf16* wob = (bf16*)alloc(256 * 512 * 2);
  float* An = (float*)alloc(512 * 16 * 4);
  int* flags = (int*)alloc(512 * 4);

  constexpr int prep_n = 1024 * 256 + 48 * 512 + 256 * 512 + DI;
  prep_kernel<<<dim3((prep_n + 255) / 256), dim3(256), 0, stream>>>(w_in, w_x, w_out, a_log, w1b, wxb, wob, An, flags);
  ln_kernel<<<dim3(M / 4), dim3(256), 0, stream>>>(x, ln_w, ln_b, xn);
  gemm_nt<1024, 256, true, false><<<dim3((M / 128) * 8), dim3(256), 0, stream>>>(xn, w1b, (void*)xzb, nullptr);
  conv_silu<<<dim3(SEQ / 8, BATCH), dim3(256), 0, stream>>>(xzb, conv_w, conv_b, xcb);
  gemm_xproj<<<dim3(M / 64), dim3(256), 0, stream>>>(xcb, wxb, dbc);
  scan_pass1<<<dim3(NC, BATCH), dim3(256), 0, stream>>>(xcb, dbc, An, flags, w_dt, b_dt, dtb_, U, SD);
  scan_pass2<<<dim3(BATCH * DI * 16 / 256), dim3(256), 0, stream>>>(SD, U, An);
  scan_pass3<<<dim3(NC, BATCH), dim3(256), 0, stream>>>(dtb_, xcb, xzb, dbc, An, flags, U, d_par, ygb);
  gemm_nt<256, 512, false, true><<<dim3((M / 128) * 2), dim3(256), 0, stream>>>(ygb, wob, d_out, x);
}

// Round 12
// 281.058 us; speedup vs baseline: 1.0359x; 1.0359x over previous
//
#include <hip/hip_runtime.h>
#include <cstdint>

#define DEVI __device__ __forceinline__

typedef __bf16 bf16;
typedef __bf16 bf16x8 __attribute__((ext_vector_type(8)));
typedef __bf16 bf16x4 __attribute__((ext_vector_type(4)));
typedef __bf16 bf16x2 __attribute__((ext_vector_type(2)));
typedef float floatx4 __attribute__((ext_vector_type(4)));
typedef float f32x2 __attribute__((ext_vector_type(2)));

constexpr int BATCH = 16, SEQ = 2048, DM = 256, DI = 512;
constexpr int M = BATCH * SEQ;   // 32768 rows
constexpr int NC = 64;           // scan chunks per sequence
constexpr int CL = SEQ / NC;     // 32 steps per chunk
constexpr int SC = 8;            // steps per staged sub-chunk (pass1)
constexpr int NSC = CL / SC;     // 4 sub-chunks
static_assert(NC * CL == SEQ, "chunking");
constexpr float LOG2E = 1.4426950408889634f;

// ---- async global->LDS (16B per lane, wave-uniform base + lane*16) ----
DEVI void gl2lds16(const void* g, void* l) {
  __builtin_amdgcn_global_load_lds(
      (const __attribute__((address_space(1))) unsigned int*)(uintptr_t)g,
      (__attribute__((address_space(3))) unsigned int*)(unsigned int)(uintptr_t)l,
      16, 0, 0);
}

DEVI float sigmoidf_(float x) { return 1.f / (1.f + __expf(-x)); }
// native v_exp_f32 (computes 2^x). NOTE: "__exp2f" collides with glibc math.h macros.
DEVI float exp2_(float x) { return __builtin_amdgcn_exp2f(x); }

DEVI float bflo(unsigned u) { return __uint_as_float(u << 16); }
DEVI float bfhi(unsigned u) { return __uint_as_float(u & 0xFFFF0000u); }
DEVI f32x2 sp2(float v) { f32x2 r; r[0] = v; r[1] = v; return r; }

DEVI float softplus_(float s) { return (s > 15.f) ? s : __logf(1.f + __expf(s)); }

// dt for a pair of channels, packed: wp[r] = {dtw[e][r], dtw[e+1][r]}.
// 4 packed accumulators keep the pk_fma chain depth ~4; 16 pk_fma total.
DEVI float2 dt_pair(const float* dr, const f32x2* wp, float2 bias) {
  f32x2 a0, a1, a2, a3;
  a0[0] = bias.x; a0[1] = bias.y;
  a1[0] = 0.f; a1[1] = 0.f;
  a2[0] = 0.f; a2[1] = 0.f;
  a3[0] = 0.f; a3[1] = 0.f;
#pragma unroll
  for (int r = 0; r < 16; r += 4) {
    const float4 v = *(const float4*)(dr + r);
    a0 = a0 + sp2(v.x) * wp[r + 0];
    a1 = a1 + sp2(v.y) * wp[r + 1];
    a2 = a2 + sp2(v.z) * wp[r + 2];
    a3 = a3 + sp2(v.w) * wp[r + 3];
  }
  const f32x2 s = (a0 + a1) + (a2 + a3);
  float2 out;
  out.x = softplus_(s[0]);
  out.y = softplus_(s[1]);
  return out;
}

// round pair to bf16 (so pass1's sdt, stored dt, and pass3's replay all agree)
DEVI float2 rnd2(float2 v) {
  v.x = (float)(bf16)v.x;
  v.y = (float)(bf16)v.y;
  return v;
}

// packed powers: P[s] = d^(s+1), s=0..15 (15 pk_muls, max chain depth 4)
DEVI void powseq(f32x2 d, f32x2* P) {
  P[0] = d;
  P[1] = d * d;
  P[2] = P[1] * d;
  P[3] = P[1] * P[1];
  P[4] = P[3] * d;
  P[5] = P[3] * P[1];
  P[6] = P[3] * P[2];
  P[7] = P[3] * P[3];
  P[8] = P[7] * d;
  P[9] = P[7] * P[1];
  P[10] = P[7] * P[2];
  P[11] = P[7] * P[3];
  P[12] = P[7] * P[4];
  P[13] = P[7] * P[5];
  P[14] = P[7] * P[6];
  P[15] = P[7] * P[7];
}

// ---- bulk stager: 8 rows x 512 e (bf16) into LDS, 512 chunks of 16B ----
DEVI void stage_rows(const bf16* src, bf16* dst, int tid) {
  gl2lds16((const char*)src + tid * 16, (char*)dst + tid * 16);
  gl2lds16((const char*)src + tid * 16 + 4096, (char*)dst + tid * 16 + 4096);
}

// =================== prep: weights fp32 -> bf16, A2 = -exp(A_log)*log2e, power-law flag ===================
__global__ __launch_bounds__(256) void prep_kernel(
    const float* __restrict__ w1, const float* __restrict__ wx,
    const float* __restrict__ wo, const float* __restrict__ alog,
    bf16* __restrict__ w1b, bf16* __restrict__ wxb, bf16* __restrict__ wob,
    float* __restrict__ An, int* __restrict__ flags) {
  constexpr int n1 = 1024 * 256, n2 = 48 * 512, n3 = 256 * 512;
  int i = blockIdx.x * 256 + threadIdx.x;
  if (i < n1) w1b[i] = (bf16)w1[i];
  else if (i < n1 + n2) wxb[i - n1] = (bf16)wx[i - n1];
  else if (i < n1 + n2 + n3) wob[i - n1 - n2] = (bf16)wo[i - n1 - n2];
  else if (i < n1 + n2 + n3 + DI) {
    const int e = i - (n1 + n2 + n3);
    const float a0 = -__expf(alog[e * 16]);
    bool ok = (a0 < 0.f);
#pragma unroll 1
    for (int s = 0; s < 16; s++) {
      const float a = -__expf(alog[e * 16 + s]);
      An[e * 16 + s] = a * LOG2E;
      ok = ok && (__builtin_fabsf(a / a0 - (float)(s + 1)) < 1e-3f);
    }
    flags[e] = ok ? 1 : 0;
  }
}

// =================== LayerNorm: one wave per 256-col row, bf16 out ===================
__global__ __launch_bounds__(256) void ln_kernel(
    const float* __restrict__ x, const float* __restrict__ w,
    const float* __restrict__ b, bf16* __restrict__ xn) {
  const int row = blockIdx.x * 4 + (threadIdx.x >> 6);
  const int lane = threadIdx.x & 63;
  const float4 v = ((const float4*)(x + (size_t)row * DM))[lane];
  float s = v.x + v.y + v.z + v.w;
  float s2 = v.x * v.x + v.y * v.y + v.z * v.z + v.w * v.w;
#pragma unroll
  for (int m = 1; m < 64; m <<= 1) { s += __shfl_xor(s, m); s2 += __shfl_xor(s2, m); }
  const float mu = s * (1.f / DM);
  const float var = s2 * (1.f / DM) - mu * mu;
  const float rs = rsqrtf(var + 1e-5f);
  const float4 wv = ((const float4*)w)[lane];
  const float4 bv = ((const float4*)b)[lane];
  bf16x4 o;
  o[0] = (bf16)((v.x - mu) * rs * wv.x + bv.x);
  o[1] = (bf16)((v.y - mu) * rs * wv.y + bv.y);
  o[2] = (bf16)((v.z - mu) * rs * wv.z + bv.z);
  o[3] = (bf16)((v.w - mu) * rs * wv.w + bv.w);
  *(bf16x4*)(xn + (size_t)row * DM + lane * 4) = o;
}

// =================== NT bf16 GEMM: C[M,N] = A[M,K] * W[N,K]^T (m97 structure) ===================
// XCD-aware 1-D grid: xcd = id&7 owns contiguous M/8 slice (A L2-resident per XCD),
// iterates all N-tiles (W <=512KB, L2-resident). Cuts A re-reads from NB x to ~1x.
template <int N, int K, bool OUT_BF16, bool RESID>
__global__ __launch_bounds__(256) void gemm_nt(const bf16* __restrict__ A,
                                               const bf16* __restrict__ W,
                                               void* __restrict__ out,
                                               const float* __restrict__ resid) {
  constexpr int BK = 32;
  constexpr int NB = N / 128;
  constexpr int MT_PER = (M / 128) / 8;  // M-tiles per XCD
  __shared__ __align__(16) bf16 lA[128 * BK];
  __shared__ __align__(16) bf16 lB[128 * BK];
  const int tid = threadIdx.x;
  const int id = blockIdx.x;
  const int xcd = id & 7;
  const int local = id >> 3;
  const int bm = (xcd * MT_PER + local / NB) * 128;
  const int bn = (local % NB) * 128;
  const int wave = tid >> 6, lane = tid & 63;
  const int wm = (wave >> 1) * 64, wn = (wave & 1) * 64;
  const int q = lane >> 4, r = lane & 15;
  floatx4 acc[4][4] = {};
  const int c0 = wave * 64 + lane;
  const int row0 = c0 >> 2, kp = (c0 & 3) * 8;
  for (int k0 = 0; k0 < K; k0 += BK) {
    gl2lds16(A + (size_t)(bm + row0) * K + k0 + kp, lA + c0 * 8);
    gl2lds16(A + (size_t)(bm + row0 + 64) * K + k0 + kp, lA + (c0 + 256) * 8);
    gl2lds16(W + (size_t)(bn + row0) * K + k0 + kp, lB + c0 * 8);
    gl2lds16(W + (size_t)(bn + row0 + 64) * K + k0 + kp, lB + (c0 + 256) * 8);
    __syncthreads();
    bf16x8 af[4], bfr[4];
#pragma unroll
    for (int i = 0; i < 4; i++) af[i] = *(const bf16x8*)&lA[(wm + i * 16 + r) * BK + q * 8];
#pragma unroll
    for (int j = 0; j < 4; j++) bfr[j] = *(const bf16x8*)&lB[(wn + j * 16 + r) * BK + q * 8];
#pragma unroll
    for (int i = 0; i < 4; i++)
#pragma unroll
      for (int j = 0; j < 4; j++)
        acc[i][j] = __builtin_amdgcn_mfma_f32_16x16x32_bf16(af[i], bfr[j], acc[i][j], 0, 0, 0);
    __syncthreads();
  }
#pragma unroll
  for (int i = 0; i < 4; i++)
#pragma unroll
    for (int j = 0; j < 4; j++)
#pragma unroll
      for (int t = 0; t < 4; t++) {
        const int row = bm + wm + i * 16 + q * 4 + t;
        const int col = bn + wn + j * 16 + r;
        const size_t idx = (size_t)row * N + col;
        float v = acc[i][j][t];
        if constexpr (OUT_BF16) {
          ((bf16*)out)[idx] = (bf16)v;
        } else {
          if constexpr (RESID) v += resid[idx];
          ((float*)out)[idx] = v;
        }
      }
}

// =================== causal depthwise conv(4) + SiLU ===================
// thread = 2 adjacent e (packed 4B coalesced loads), 8 positions/thread.
__global__ __launch_bounds__(256) void conv_silu(const bf16* __restrict__ xz,
                                                 const float* __restrict__ cw,
                                                 const float* __restrict__ cb,
                                                 bf16* __restrict__ xc) {
  const int tid = threadIdx.x;
  const int e2 = tid * 2;              // [0,512) in steps of 2
  const int p0 = blockIdx.x * 8;
  const int b = blockIdx.y;
  const float4 w0 = ((const float4*)cw)[e2];
  const float4 w1 = ((const float4*)cw)[e2 + 1];
  const float2 bias = *(const float2*)(cb + e2);
  float xa[11], xb_[11];
#pragma unroll
  for (int j = 0; j < 11; j++) {
    const int pos = p0 - 3 + j;
    float fa = 0.f, fb = 0.f;
    if (pos >= 0) {  // block-uniform (only blockIdx.x==0 has pos<0)
      const unsigned u = *(const unsigned*)(xz + ((size_t)b * SEQ + pos) * 1024 + e2);
      fa = __uint_as_float(u << 16);
      fb = __uint_as_float(u & 0xFFFF0000u);
    }
    xa[j] = fa; xb_[j] = fb;
  }
#pragma unroll
  for (int k = 0; k < 8; k++) {
    const float a0 = bias.x + xa[k] * w0.x + xa[k + 1] * w0.y + xa[k + 2] * w0.z + xa[k + 3] * w0.w;
    const float a1 = bias.y + xb_[k] * w1.x + xb_[k + 1] * w1.y + xb_[k + 2] * w1.z + xb_[k + 3] * w1.w;
    bf16x2 o;
    o[0] = (bf16)(a0 * sigmoidf_(a0));
    o[1] = (bf16)(a1 * sigmoidf_(a1));
    *(bf16x2*)(xc + ((size_t)b * SEQ + p0 + k) * DI + e2) = o;
  }
}

// =================== x_proj: dbc[M,48] = xc[M,512] * Wx[48,512]^T ===================
// 64-row tiles (512 blocks), wave = 16 rows x 48 cols.
__global__ __launch_bounds__(256) void gemm_xproj(const bf16* __restrict__ A,
                                                  const bf16* __restrict__ W,
                                                  float* __restrict__ out) {
  constexpr int K = DI;
  __shared__ __align__(16) bf16 lW[48 * K];   // 49152 B
  __shared__ __align__(16) bf16 lA[64 * 32];  // 4096 B
  const int tid = threadIdx.x;
  const int wave = tid >> 6, lane = tid & 63;
  const int bm = blockIdx.x * 64;
  const int q = lane >> 4, r = lane & 15;
#pragma unroll
  for (int rd = 0; rd < 12; rd++) {  // 3072 chunks of 16B
    const int c = rd * 256 + tid;
    gl2lds16((const char*)W + (size_t)c * 16, (char*)lW + (size_t)c * 16);
  }
  const int row0 = tid >> 2, kp = (tid & 3) * 8;
  const int wm = wave * 16;
  floatx4 acc[3] = {};
  for (int k0 = 0; k0 < K; k0 += 32) {
    gl2lds16(A + (size_t)(bm + row0) * K + k0 + kp, lA + tid * 8);
    __syncthreads();
    bf16x8 af = *(const bf16x8*)&lA[(wm + r) * 32 + q * 8];
#pragma unroll
    for (int j = 0; j < 3; j++) {
      const bf16x8 bfr = *(const bf16x8*)&lW[(j * 16 + r) * K + k0 + q * 8];
      acc[j] = __builtin_amdgcn_mfma_f32_16x16x32_bf16(af, bfr, acc[j], 0, 0, 0);
    }
    __syncthreads();
  }
#pragma unroll
  for (int j = 0; j < 3; j++)
#pragma unroll
    for (int t = 0; t < 4; t++)
      out[(size_t)(bm + wm + q * 4 + t) * 48 + j * 16 + r] = acc[j][t];
}

// =================== scan pass1: per-chunk aggregates (dt fused + STORED; U bf16) ===================
// 2 adjacent e per thread; xc bulk-staged (dbuf); dbc[:,0:32] staged once;
// dt = softplus(dbc[:,0:16] . dtw[e] + bias) via packed-pair FMA, rounded to
// bf16 (consistent with pass3's replay), stored to dtout for pass3 to reuse.
__global__ __launch_bounds__(256) void scan_pass1(const bf16* __restrict__ xc,
                                                  const float* __restrict__ dbc,
                                                  const float* __restrict__ An,
                                                  const int* __restrict__ flags,
                                                  const float* __restrict__ dtw,
                                                  const float* __restrict__ dtb,
                                                  bf16* __restrict__ dtout,
                                                  bf16* __restrict__ U,
                                                  float* __restrict__ SD) {
  __shared__ __align__(16) float sbc[CL * 32];          // 4 KB: per pos dtr[16] B[16]
  __shared__ __align__(16) bf16 sxc_[2][SC * DI];       // 2 x 8 KB
  const int tid = threadIdx.x;
  const int e2 = tid * 2;
  const int ch = blockIdx.x, b = blockIdx.y;
  const size_t posBase = (size_t)b * SEQ + (size_t)ch * CL;
  {  // stage dbc cols 0..32 of CL rows: 256 chunks of 16B (all threads)
    const int il = tid >> 3, f = (tid & 7) * 4;
    gl2lds16(dbc + (posBase + il) * 48 + f, (char*)sbc + tid * 16);
  }
  stage_rows(xc + posBase * DI, sxc_[0], tid);
  const int2 fl = *(const int2*)(flags + e2);
  const int fast = fl.x & fl.y;
  f32x2 h[16];
#pragma unroll
  for (int s = 0; s < 16; s++) { h[s][0] = 0.f; h[s][1] = 0.f; }
  f32x2 sdt2; sdt2[0] = 0.f; sdt2[1] = 0.f;
  f32x2 A02; A02[0] = An[(size_t)e2 * 16]; A02[1] = An[(size_t)e2 * 16 + 16];
  // dt weights as packed pairs wp[r] = {dtw[e2][r], dtw[e2+1][r]}
  f32x2 wp[16];
#pragma unroll
  for (int r = 0; r < 16; r += 4) {
    float4 t0 = *(const float4*)(dtw + (size_t)e2 * 16 + r);
    float4 t1 = *(const float4*)(dtw + (size_t)(e2 + 1) * 16 + r);
    wp[r + 0][0] = t0.x; wp[r + 0][1] = t1.x;
    wp[r + 1][0] = t0.y; wp[r + 1][1] = t1.y;
    wp[r + 2][0] = t0.z; wp[r + 2][1] = t1.z;
    wp[r + 3][0] = t0.w; wp[r + 3][1] = t1.w;
  }
  const float2 bias = *(const float2*)(dtb + e2);
  __syncthreads();
  float2 dtc = rnd2(dt_pair(sbc, wp, bias));  // dt for step 0 (bf16-rounded)
#pragma unroll 1
  for (int sc = 0; sc < NSC; sc++) {
    const int cb = sc & 1;
    if (sc + 1 < NSC)
      stage_rows(xc + (posBase + (sc + 1) * SC) * DI, sxc_[cb ^ 1], tid);
    const char* sxcb = (const char*)sxc_[cb];
    const int tid4 = tid * 4;
    if (fast) {
#pragma unroll 2
      for (int il = 0; il < SC; il++) {
        const int ig = sc * SC + il;
        const int ng = (ig + 1 < CL) ? (ig + 1) : ig;
        const float2 dtn = rnd2(dt_pair(sbc + ng * 32, wp, bias));
        const unsigned ux = *(const unsigned*)(sxcb + il * 1024 + tid4);
        bf16x2 dto; dto[0] = (bf16)dtc.x; dto[1] = (bf16)dtc.y;
        *(bf16x2*)(dtout + (posBase + ig) * DI + e2) = dto;
        f32x2 dt2; dt2[0] = dtc.x; dt2[1] = dtc.y;
        f32x2 xv2; xv2[0] = bflo(ux); xv2[1] = bfhi(ux);
        const f32x2 dtx2 = dt2 * xv2;
        sdt2 = sdt2 + dt2;
        const f32x2 t = dt2 * A02;
        f32x2 d; d[0] = exp2_(t[0]); d[1] = exp2_(t[1]);
        f32x2 P[16];
        powseq(d, P);
        const float4* bb = (const float4*)(sbc + ig * 32 + 16);
#pragma unroll
        for (int g = 0; g < 4; g++) {
          const float4 B4 = bb[g];
          h[4 * g + 0] = P[4 * g + 0] * h[4 * g + 0] + dtx2 * sp2(B4.x);
          h[4 * g + 1] = P[4 * g + 1] * h[4 * g + 1] + dtx2 * sp2(B4.y);
          h[4 * g + 2] = P[4 * g + 2] * h[4 * g + 2] + dtx2 * sp2(B4.z);
          h[4 * g + 3] = P[4 * g + 3] * h[4 * g + 3] + dtx2 * sp2(B4.w);
        }
        dtc = dtn;
      }
    } else {
      // cold path (flags pattern broken): A read via volatile to avoid
      // register promotion; correctness identical.
      const volatile float* Ap = An + (size_t)e2 * 16;
      const volatile float* Bp = An + (size_t)e2 * 16 + 16;
#pragma unroll 1
      for (int il = 0; il < SC; il++) {
        const int ig = sc * SC + il;
        const int ng = (ig + 1 < CL) ? (ig + 1) : ig;
        const float2 dtn = rnd2(dt_pair(sbc + ng * 32, wp, bias));
        const unsigned ux = *(const unsigned*)(sxcb + il * 1024 + tid4);
        bf16x2 dto; dto[0] = (bf16)dtc.x; dto[1] = (bf16)dtc.y;
        *(bf16x2*)(dtout + (posBase + ig) * DI + e2) = dto;
        const float dta = dtc.x, dtb_v = dtc.y;
        const float xa = bflo(ux), xb = bfhi(ux);
        const float dtxa = dta * xa, dtxb = dtb_v * xb;
        sdt2[0] += dta; sdt2[1] += dtb_v;
        const float* bc = sbc + ig * 32 + 16;
#pragma unroll 1
        for (int s = 0; s < 16; s++) {
          const float bv = bc[s];
          h[s][0] = exp2_(dta * Ap[s]) * h[s][0] + dtxa * bv;
          h[s][1] = exp2_(dtb_v * Bp[s]) * h[s][1] + dtxb * bv;
        }
        dtc = dtn;
      }
    }
    __syncthreads();  // drain staging + protect buffer reuse
  }
  bf16* up = U + ((size_t)(b * NC + ch) * DI + e2) * 16;
  bf16x8 oa0, oa1, ob0, ob1;
#pragma unroll
  for (int i = 0; i < 8; i++) {
    oa0[i] = (bf16)h[i][0];
    oa1[i] = (bf16)h[8 + i][0];
    ob0[i] = (bf16)h[i][1];
    ob1[i] = (bf16)h[8 + i][1];
  }
  *(bf16x8*)(up) = oa0;
  *(bf16x8*)(up + 8) = oa1;
  *(bf16x8*)(up + 16) = ob0;
  *(bf16x8*)(up + 24) = ob1;
  float2 sdo; sdo.x = sdt2[0]; sdo.y = sdt2[1];
  *(float2*)(SD + (size_t)(b * NC + ch) * DI + e2) = sdo;
}

// =================== scan pass2: combine chunk aggregates (U bf16), parallel over (b,e,s) ===================
// group-of-16 pipelined loads; running h stays f32, stored h0 rounds to bf16.
__global__ __launch_bounds__(256) void scan_pass2(const float* __restrict__ SD,
                                                  bf16* U,
                                                  const float* __restrict__ An) {
  const int t = blockIdx.x * 256 + threadIdx.x;  // over BATCH*DI*16
  const int s = t & 15;
  const int e = (t >> 4) & (DI - 1);
  const int b = t >> 13;
  const float Av = An[e * 16 + s];  // pre-scaled by log2e
  const float* sdp = SD + (size_t)b * NC * DI + e;
  bf16* up = U + ((size_t)b * NC * DI + e) * 16 + s;
  float sA_[16], uA_[16], sB_[16], uB_[16];
#pragma unroll
  for (int j = 0; j < 16; j++) {
    sA_[j] = sdp[(size_t)j * DI];
    uA_[j] = (float)up[(size_t)j * DI * 16];
  }
  float h = 0.f;
#pragma unroll 1
  for (int c0 = 0; c0 < NC; c0 += 32) {
#pragma unroll
    for (int j = 0; j < 16; j++) {
      sB_[j] = sdp[(size_t)(c0 + 16 + j) * DI];
      uB_[j] = (float)up[(size_t)(c0 + 16 + j) * DI * 16];
    }
#pragma unroll
    for (int j = 0; j < 16; j++) {
      const float h0 = h;
      h = exp2_(Av * sA_[j]) * h0 + uA_[j];
      up[(size_t)(c0 + j) * DI * 16] = (bf16)h0;
    }
    const int nn = (c0 + 32 < NC) ? (c0 + 32) : (NC - 16);
#pragma unroll
    for (int j = 0; j < 16; j++) {
      sA_[j] = sdp[(size_t)(nn + j) * DI];
      uA_[j] = (float)up[(size_t)(nn + j) * DI * 16];
    }
#pragma unroll
    for (int j = 0; j < 16; j++) {
      const float h0 = h;
      h = exp2_(Av * sB_[j]) * h0 + uB_[j];
      up[(size_t)(c0 + 16 + j) * DI * 16] = (bf16)h0;
    }
  }
}

// =================== scan pass3: replay chunk from true h0 (bf16), emit gated y ===================
// 2 adjacent e per thread; software-pipelined global loads (prefetch il+1).
// dt read from pass1's stored buffer; slow-path A via volatile (VGPR trim).
__global__ __launch_bounds__(256) void scan_pass3(const bf16* __restrict__ dt,
                                                  const bf16* __restrict__ xc,
                                                  const bf16* __restrict__ xz,
                                                  const float* __restrict__ dbc,
                                                  const float* __restrict__ An,
                                                  const int* __restrict__ flags,
                                                  const bf16* __restrict__ H0,
                                                  const float* __restrict__ Dp,
                                                  bf16* __restrict__ yg) {
  __shared__ __align__(16) float sbc[CL * 32];  // per pos: B[16] C[16]
  const int tid = threadIdx.x;
  const int e2 = tid * 2;
  const int ch = blockIdx.x, b = blockIdx.y;
  const size_t posBase = (size_t)b * SEQ + (size_t)ch * CL;
  {
    const int il = tid >> 3, f = (tid & 7) * 4;
    gl2lds16(dbc + (posBase + il) * 48 + 16 + f, (char*)sbc + tid * 16);
  }
  const int2 fl = *(const int2*)(flags + e2);
  const int fast = fl.x & fl.y;
  f32x2 h[16];
  const bf16* hp = H0 + ((size_t)(b * NC + ch) * DI + e2) * 16;
  {
    const bf16x8 ha0 = *(const bf16x8*)(hp);
    const bf16x8 ha1 = *(const bf16x8*)(hp + 8);
    const bf16x8 hb0 = *(const bf16x8*)(hp + 16);
    const bf16x8 hb1 = *(const bf16x8*)(hp + 24);
#pragma unroll
    for (int i = 0; i < 8; i++) {
      h[i][0] = (float)ha0[i];
      h[8 + i][0] = (float)ha1[i];
      h[i][1] = (float)hb0[i];
      h[8 + i][1] = (float)hb1[i];
    }
  }
  const float2 Dv = *(const float2*)(Dp + e2);
  f32x2 Dv2; Dv2[0] = Dv.x; Dv2[1] = Dv.y;
  f32x2 A02; A02[0] = An[(size_t)e2 * 16]; A02[1] = An[(size_t)e2 * 16 + 16];
  // prefetch il=0
  const char* pdt = (const char*)(dt + posBase * DI + e2);
  const char* pxc = (const char*)(xc + posBase * DI + e2);
  const char* pxz = (const char*)(xz + posBase * 1024 + DI + e2);
  unsigned ud = *(const unsigned*)pdt;
  unsigned ux = *(const unsigned*)pxc;
  unsigned uz = *(const unsigned*)pxz;
  __syncthreads();
  if (fast) {
#pragma unroll 1
    for (int il = 0; il < CL; il++) {
      const int np = (il + 1 < CL) ? (il + 1) : il;
      const unsigned nud = *(const unsigned*)(pdt + (size_t)np * DI * 2);
      const unsigned nux = *(const unsigned*)(pxc + (size_t)np * DI * 2);
      const unsigned nuz = *(const unsigned*)(pxz + (size_t)np * 1024 * 2);
      const size_t pos = posBase + il;
      f32x2 dt2; dt2[0] = bflo(ud); dt2[1] = bfhi(ud);
      f32x2 xv2; xv2[0] = bflo(ux); xv2[1] = bfhi(ux);
      f32x2 z2; z2[0] = bflo(uz); z2[1] = bfhi(uz);
      const f32x2 dtx2 = dt2 * xv2;
      const f32x2 t = dt2 * A02;
      f32x2 d; d[0] = exp2_(t[0]); d[1] = exp2_(t[1]);
      f32x2 P[16];
      powseq(d, P);
      const float4* bb = (const float4*)(sbc + il * 32);
      f32x2 Yv[4];
#pragma unroll
      for (int g = 0; g < 4; g++) { Yv[g][0] = 0.f; Yv[g][1] = 0.f; }
#pragma unroll
      for (int g = 0; g < 4; g++) {
        const float4 B4 = bb[g];
        const float4 C4 = bb[4 + g];
        h[4 * g + 0] = P[4 * g + 0] * h[4 * g + 0] + dtx2 * sp2(B4.x);
        Yv[g] = Yv[g] + h[4 * g + 0] * sp2(C4.x);
        h[4 * g + 1] = P[4 * g + 1] * h[4 * g + 1] + dtx2 * sp2(B4.y);
        Yv[g] = Yv[g] + h[4 * g + 1] * sp2(C4.y);
        h[4 * g + 2] = P[4 * g + 2] * h[4 * g + 2] + dtx2 * sp2(B4.z);
        Yv[g] = Yv[g] + h[4 * g + 2] * sp2(C4.z);
        h[4 * g + 3] = P[4 * g + 3] * h[4 * g + 3] + dtx2 * sp2(B4.w);
        Yv[g] = Yv[g] + h[4 * g + 3] * sp2(C4.w);
      }
      const f32x2 Ys = (Yv[0] + Yv[1]) + (Yv[2] + Yv[3]);
      f32x2 gz; gz[0] = z2[0] * sigmoidf_(z2[0]); gz[1] = z2[1] * sigmoidf_(z2[1]);
      const f32x2 yv2 = (Ys + Dv2 * xv2) * gz;
      bf16x2 o; o[0] = (bf16)yv2[0]; o[1] = (bf16)yv2[1];
      *(bf16x2*)(yg + pos * DI + e2) = o;
      ud = nud; ux = nux; uz = nuz;
    }
  } else {
    // cold path: A via volatile (keeps 32 A-values out of static VGPR count)
    const volatile float* Ap = An + (size_t)e2 * 16;
    const volatile float* Bp = An + (size_t)e2 * 16 + 16;
#pragma unroll 1
    for (int il = 0; il < CL; il++) {
      const int np = (il + 1 < CL) ? (il + 1) : il;
      const unsigned nud = *(const unsigned*)(pdt + (size_t)np * DI * 2);
      const unsigned nux = *(const unsigned*)(pxc + (size_t)np * DI * 2);
      const unsigned nuz = *(const unsigned*)(pxz + (size_t)np * 1024 * 2);
      const size_t pos = posBase + il;
      const float dta = bflo(ud), dtb_v = bfhi(ud);
      const float xa = bflo(ux), xb = bfhi(ux);
      const float za = bflo(uz), zb = bfhi(uz);
      const float dtxa = dta * xa, dtxb = dtb_v * xb;
      const float* bc = sbc + il * 32;
      float ya = 0.f, yb = 0.f;
#pragma unroll 1
      for (int s = 0; s < 16; s++) {
        const float bv = bc[s], cv = bc[16 + s];
        const float ha = exp2_(dta * Ap[s]) * h[s][0] + dtxa * bv;
        const float hb = exp2_(dtb_v * Bp[s]) * h[s][1] + dtxb * bv;
        h[s][0] = ha; h[s][1] = hb;
        ya += ha * cv; yb += hb * cv;
      }
      const float yva = (ya + Dv.x * xa) * za * sigmoidf_(za);
      const float yvb = (yb + Dv.y * xb) * zb * sigmoidf_(zb);
      bf16x2 o; o[0] = (bf16)yva; o[1] = (bf16)yvb;
      *(bf16x2*)(yg + pos * DI + e2) = o;
      ud = nud; ux = nux; uz = nuz;
    }
  }
}

// =================== host ===================
extern "C" void kernel_launch(void* const* d_in, const int* in_sizes, int n_in,
                              void* d_out, int out_size, void* d_ws, size_t ws_size,
                              hipStream_t stream) {
  const float* x = (const float*)d_in[0];
  const float* ln_w = (const float*)d_in[1];
  const float* ln_b = (const float*)d_in[2];
  const float* w_in = (const float*)d_in[3];
  const float* conv_w = (const float*)d_in[4];
  const float* conv_b = (const float*)d_in[5];
  const float* w_x = (const float*)d_in[6];
  const float* w_dt = (const float*)d_in[7];
  const float* b_dt = (const float*)d_in[8];
  const float* a_log = (const float*)d_in[9];
  const float* d_par = (const float*)d_in[10];
  const float* w_out = (const float*)d_in[11];

  char* ws = (char*)d_ws;
  size_t off = 0;
  auto alloc = [&](size_t bytes) {
    void* p = ws + off;
    off = (off + bytes + 255) & ~(size_t)255;
    return p;
  };
  bf16* xzb = (bf16*)alloc((size_t)M * 1024 * 2);
  bf16* xcb = (bf16*)alloc((size_t)M * DI * 2);
  float* dbc = (float*)alloc((size_t)M * 48 * 4);
  bf16* dtb_ = (bf16*)alloc((size_t)M * DI * 2);
  bf16* ygb = (bf16*)alloc((size_t)M * DI * 2);
  bf16* U = (bf16*)alloc((size_t)BATCH * NC * DI * 16 * 2);  // 16.75 MB (bf16)
  bf16* xn = (bf16*)U;  // alias: xn (16MB) dead before U's first write (pass1 after gemm#1)
  float* SD = (float*)alloc((size_t)BATCH * NC * DI * 4);    // 2.1 MB
  bf16* w1b = (bf16*)alloc(1024 * 256 * 2);
  bf16* wxb = (bf16*)alloc(48 * 512 * 2);
  bf16* wob = (bf16*)alloc(256 * 512 * 2);
  float* An = (float*)alloc(512 * 16 * 4);
  int* flags = (int*)alloc(512 * 4);

  constexpr int prep_n = 1024 * 256 + 48 * 512 + 256 * 512 + DI;
  prep_kernel<<<dim3((prep_n + 255) / 256), dim3(256), 0, stream>>>(w_in, w_x, w_out, a_log, w1b, wxb, wob, An, flags);
  ln_kernel<<<dim3(M / 4), dim3(256), 0, stream>>>(x, ln_w, ln_b, xn);
  gemm_nt<1024, 256, true, false><<<dim3((M / 128) * 8), dim3(256), 0, stream>>>(xn, w1b, (void*)xzb, nullptr);
  conv_silu<<<dim3(SEQ / 8, BATCH), dim3(256), 0, stream>>>(xzb, conv_w, conv_b, xcb);
  gemm_xproj<<<dim3(M / 64), dim3(256), 0, stream>>>(xcb, wxb, dbc);
  scan_pass1<<<dim3(NC, BATCH), dim3(256), 0, stream>>>(xcb, dbc, An, flags, w_dt, b_dt, dtb_, U, SD);
  scan_pass2<<<dim3(BATCH * DI * 16 / 256), dim3(256), 0, stream>>>(SD, U, An);
  scan_pass3<<<dim3(NC, BATCH), dim3(256), 0, stream>>>(dtb_, xcb, xzb, dbc, An, flags, U, d_par, ygb);
  gemm_nt<256, 512, false, true><<<dim3((M / 128) * 2), dim3(256), 0, stream>>>(ygb, wob, d_out, x);
}

// Round 13
// 276.129 us; speedup vs baseline: 1.0544x; 1.0179x over previous
//
#include <hip/hip_runtime.h>
#include <cstdint>

#define DEVI __device__ __forceinline__

typedef __bf16 bf16;
typedef __bf16 bf16x8 __attribute__((ext_vector_type(8)));
typedef __bf16 bf16x4 __attribute__((ext_vector_type(4)));
typedef __bf16 bf16x2 __attribute__((ext_vector_type(2)));
typedef float floatx4 __attribute__((ext_vector_type(4)));
typedef float f32x2 __attribute__((ext_vector_type(2)));

constexpr int BATCH = 16, SEQ = 2048, DM = 256, DI = 512;
constexpr int M = BATCH * SEQ;   // 32768 rows
constexpr int NC = 64;           // scan chunks per sequence
constexpr int CL = SEQ / NC;     // 32 steps per chunk
constexpr int SC = 8;            // steps per staged sub-chunk (pass1)
constexpr int NSC = CL / SC;     // 4 sub-chunks
static_assert(NC * CL == SEQ, "chunking");
constexpr float LOG2E = 1.4426950408889634f;

// ---- async global->LDS (16B per lane, wave-uniform base + lane*16) ----
DEVI void gl2lds16(const void* g, void* l) {
  __builtin_amdgcn_global_load_lds(
      (const __attribute__((address_space(1))) unsigned int*)(uintptr_t)g,
      (__attribute__((address_space(3))) unsigned int*)(unsigned int)(uintptr_t)l,
      16, 0, 0);
}

DEVI float sigmoidf_(float x) { return 1.f / (1.f + __expf(-x)); }
// native v_exp_f32 (computes 2^x). NOTE: "__exp2f" collides with glibc math.h macros.
DEVI float exp2_(float x) { return __builtin_amdgcn_exp2f(x); }

DEVI float bflo(unsigned u) { return __uint_as_float(u << 16); }
DEVI float bfhi(unsigned u) { return __uint_as_float(u & 0xFFFF0000u); }
DEVI f32x2 sp2(float v) { f32x2 r; r[0] = v; r[1] = v; return r; }

DEVI float softplus_(float s) { return (s > 15.f) ? s : __logf(1.f + __expf(s)); }

// dt for a pair of channels, packed: wp[r] = {dtw[e][r], dtw[e+1][r]}.
// 4 packed accumulators keep the pk_fma chain depth ~4; 16 pk_fma total.
DEVI float2 dt_pair(const float* dr, const f32x2* wp, float2 bias) {
  f32x2 a0, a1, a2, a3;
  a0[0] = bias.x; a0[1] = bias.y;
  a1[0] = 0.f; a1[1] = 0.f;
  a2[0] = 0.f; a2[1] = 0.f;
  a3[0] = 0.f; a3[1] = 0.f;
#pragma unroll
  for (int r = 0; r < 16; r += 4) {
    const float4 v = *(const float4*)(dr + r);
    a0 = a0 + sp2(v.x) * wp[r + 0];
    a1 = a1 + sp2(v.y) * wp[r + 1];
    a2 = a2 + sp2(v.z) * wp[r + 2];
    a3 = a3 + sp2(v.w) * wp[r + 3];
  }
  const f32x2 s = (a0 + a1) + (a2 + a3);
  float2 out;
  out.x = softplus_(s[0]);
  out.y = softplus_(s[1]);
  return out;
}

// round pair to bf16 (so pass1's sdt, stored dt, and pass3's replay all agree)
DEVI float2 rnd2(float2 v) {
  v.x = (float)(bf16)v.x;
  v.y = (float)(bf16)v.y;
  return v;
}

// packed powers: P[s] = d^(s+1), s=0..15 (15 pk_muls, max chain depth 4)
DEVI void powseq(f32x2 d, f32x2* P) {
  P[0] = d;
  P[1] = d * d;
  P[2] = P[1] * d;
  P[3] = P[1] * P[1];
  P[4] = P[3] * d;
  P[5] = P[3] * P[1];
  P[6] = P[3] * P[2];
  P[7] = P[3] * P[3];
  P[8] = P[7] * d;
  P[9] = P[7] * P[1];
  P[10] = P[7] * P[2];
  P[11] = P[7] * P[3];
  P[12] = P[7] * P[4];
  P[13] = P[7] * P[5];
  P[14] = P[7] * P[6];
  P[15] = P[7] * P[7];
}

// ---- bulk stager: 8 rows x 512 e (bf16) into LDS, 512 chunks of 16B ----
DEVI void stage_rows(const bf16* src, bf16* dst, int tid) {
  gl2lds16((const char*)src + tid * 16, (char*)dst + tid * 16);
  gl2lds16((const char*)src + tid * 16 + 4096, (char*)dst + tid * 16 + 4096);
}

// =================== prep: weights fp32 -> bf16, A2 = -exp(A_log)*log2e, power-law flag ===================
__global__ __launch_bounds__(256) void prep_kernel(
    const float* __restrict__ w1, const float* __restrict__ wx,
    const float* __restrict__ wo, const float* __restrict__ alog,
    bf16* __restrict__ w1b, bf16* __restrict__ wxb, bf16* __restrict__ wob,
    float* __restrict__ An, int* __restrict__ flags) {
  constexpr int n1 = 1024 * 256, n2 = 48 * 512, n3 = 256 * 512;
  int i = blockIdx.x * 256 + threadIdx.x;
  if (i < n1) w1b[i] = (bf16)w1[i];
  else if (i < n1 + n2) wxb[i - n1] = (bf16)wx[i - n1];
  else if (i < n1 + n2 + n3) wob[i - n1 - n2] = (bf16)wo[i - n1 - n2];
  else if (i < n1 + n2 + n3 + DI) {
    const int e = i - (n1 + n2 + n3);
    const float a0 = -__expf(alog[e * 16]);
    bool ok = (a0 < 0.f);
#pragma unroll 1
    for (int s = 0; s < 16; s++) {
      const float a = -__expf(alog[e * 16 + s]);
      An[e * 16 + s] = a * LOG2E;
      ok = ok && (__builtin_fabsf(a / a0 - (float)(s + 1)) < 1e-3f);
    }
    flags[e] = ok ? 1 : 0;
  }
}

// =================== LayerNorm: one wave per 256-col row, bf16 out ===================
__global__ __launch_bounds__(256) void ln_kernel(
    const float* __restrict__ x, const float* __restrict__ w,
    const float* __restrict__ b, bf16* __restrict__ xn) {
  const int row = blockIdx.x * 4 + (threadIdx.x >> 6);
  const int lane = threadIdx.x & 63;
  const float4 v = ((const float4*)(x + (size_t)row * DM))[lane];
  float s = v.x + v.y + v.z + v.w;
  float s2 = v.x * v.x + v.y * v.y + v.z * v.z + v.w * v.w;
#pragma unroll
  for (int m = 1; m < 64; m <<= 1) { s += __shfl_xor(s, m); s2 += __shfl_xor(s2, m); }
  const float mu = s * (1.f / DM);
  const float var = s2 * (1.f / DM) - mu * mu;
  const float rs = rsqrtf(var + 1e-5f);
  const float4 wv = ((const float4*)w)[lane];
  const float4 bv = ((const float4*)b)[lane];
  bf16x4 o;
  o[0] = (bf16)((v.x - mu) * rs * wv.x + bv.x);
  o[1] = (bf16)((v.y - mu) * rs * wv.y + bv.y);
  o[2] = (bf16)((v.z - mu) * rs * wv.z + bv.z);
  o[3] = (bf16)((v.w - mu) * rs * wv.w + bv.w);
  *(bf16x4*)(xn + (size_t)row * DM + lane * 4) = o;
}

// =================== NT bf16 GEMM: C[M,N] = A[M,K] * W[N,K]^T (BK=64) ===================
// XCD-aware 1-D grid: xcd = id&7 owns contiguous M/8 slice (A L2-resident per XCD),
// iterates all N-tiles (W <=512KB, L2-resident). BK=64 halves barrier count vs BK=32
// (short-K kernels are barrier-drain-bound); LDS 32KB keeps ~4 blocks/CU.
template <int N, int K, bool OUT_BF16, bool RESID>
__global__ __launch_bounds__(256) void gemm_nt(const bf16* __restrict__ A,
                                               const bf16* __restrict__ W,
                                               void* __restrict__ out,
                                               const float* __restrict__ resid) {
  constexpr int BK = 64;
  constexpr int NB = N / 128;
  constexpr int MT_PER = (M / 128) / 8;  // M-tiles per XCD
  __shared__ __align__(16) bf16 lA[128 * BK];  // 16 KB
  __shared__ __align__(16) bf16 lB[128 * BK];  // 16 KB
  const int tid = threadIdx.x;
  const int id = blockIdx.x;
  const int xcd = id & 7;
  const int local = id >> 3;
  const int bm = (xcd * MT_PER + local / NB) * 128;
  const int bn = (local % NB) * 128;
  const int wave = tid >> 6, lane = tid & 63;
  const int wm = (wave >> 1) * 64, wn = (wave & 1) * 64;
  const int q = lane >> 4, r = lane & 15;
  floatx4 acc[4][4] = {};
  for (int k0 = 0; k0 < K; k0 += BK) {
    // stage 128x64 tiles: 4 calls of 256 threads x 16B per matrix
#pragma unroll
    for (int cc = 0; cc < 4; cc++) {
      const int c = cc * 256 + tid;
      const int rw = c >> 3, kk = (c & 7) * 8;
      gl2lds16(A + (size_t)(bm + rw) * K + k0 + kk, lA + c * 8);
      gl2lds16(W + (size_t)(bn + rw) * K + k0 + kk, lB + c * 8);
    }
    __syncthreads();
#pragma unroll
    for (int kh = 0; kh < 2; kh++) {
      bf16x8 af[4], bfr[4];
#pragma unroll
      for (int i = 0; i < 4; i++) af[i] = *(const bf16x8*)&lA[(wm + i * 16 + r) * BK + kh * 32 + q * 8];
#pragma unroll
      for (int j = 0; j < 4; j++) bfr[j] = *(const bf16x8*)&lB[(wn + j * 16 + r) * BK + kh * 32 + q * 8];
#pragma unroll
      for (int i = 0; i < 4; i++)
#pragma unroll
        for (int j = 0; j < 4; j++)
          acc[i][j] = __builtin_amdgcn_mfma_f32_16x16x32_bf16(af[i], bfr[j], acc[i][j], 0, 0, 0);
    }
    __syncthreads();
  }
#pragma unroll
  for (int i = 0; i < 4; i++)
#pragma unroll
    for (int j = 0; j < 4; j++)
#pragma unroll
      for (int t = 0; t < 4; t++) {
        const int row = bm + wm + i * 16 + q * 4 + t;
        const int col = bn + wn + j * 16 + r;
        const size_t idx = (size_t)row * N + col;
        float v = acc[i][j][t];
        if constexpr (OUT_BF16) {
          ((bf16*)out)[idx] = (bf16)v;
        } else {
          if constexpr (RESID) v += resid[idx];
          ((float*)out)[idx] = v;
        }
      }
}

// =================== causal depthwise conv(4) + SiLU ===================
// thread = 2 adjacent e (packed 4B coalesced loads), 8 positions/thread.
__global__ __launch_bounds__(256) void conv_silu(const bf16* __restrict__ xz,
                                                 const float* __restrict__ cw,
                                                 const float* __restrict__ cb,
                                                 bf16* __restrict__ xc) {
  const int tid = threadIdx.x;
  const int e2 = tid * 2;              // [0,512) in steps of 2
  const int p0 = blockIdx.x * 8;
  const int b = blockIdx.y;
  const float4 w0 = ((const float4*)cw)[e2];
  const float4 w1 = ((const float4*)cw)[e2 + 1];
  const float2 bias = *(const float2*)(cb + e2);
  float xa[11], xb_[11];
#pragma unroll
  for (int j = 0; j < 11; j++) {
    const int pos = p0 - 3 + j;
    float fa = 0.f, fb = 0.f;
    if (pos >= 0) {  // block-uniform (only blockIdx.x==0 has pos<0)
      const unsigned u = *(const unsigned*)(xz + ((size_t)b * SEQ + pos) * 1024 + e2);
      fa = __uint_as_float(u << 16);
      fb = __uint_as_float(u & 0xFFFF0000u);
    }
    xa[j] = fa; xb_[j] = fb;
  }
#pragma unroll
  for (int k = 0; k < 8; k++) {
    const float a0 = bias.x + xa[k] * w0.x + xa[k + 1] * w0.y + xa[k + 2] * w0.z + xa[k + 3] * w0.w;
    const float a1 = bias.y + xb_[k] * w1.x + xb_[k + 1] * w1.y + xb_[k + 2] * w1.z + xb_[k + 3] * w1.w;
    bf16x2 o;
    o[0] = (bf16)(a0 * sigmoidf_(a0));
    o[1] = (bf16)(a1 * sigmoidf_(a1));
    *(bf16x2*)(xc + ((size_t)b * SEQ + p0 + k) * DI + e2) = o;
  }
}

// =================== x_proj: dbc[M,48] = xc[M,512] * Wx[48,512]^T ===================
// 64-row tiles (512 blocks), wave = 16 rows x 48 cols.
__global__ __launch_bounds__(256) void gemm_xproj(const bf16* __restrict__ A,
                                                  const bf16* __restrict__ W,
                                                  float* __restrict__ out) {
  constexpr int K = DI;
  __shared__ __align__(16) bf16 lW[48 * K];   // 49152 B
  __shared__ __align__(16) bf16 lA[64 * 32];  // 4096 B
  const int tid = threadIdx.x;
  const int wave = tid >> 6, lane = tid & 63;
  const int bm = blockIdx.x * 64;
  const int q = lane >> 4, r = lane & 15;
#pragma unroll
  for (int rd = 0; rd < 12; rd++) {  // 3072 chunks of 16B
    const int c = rd * 256 + tid;
    gl2lds16((const char*)W + (size_t)c * 16, (char*)lW + (size_t)c * 16);
  }
  const int row0 = tid >> 2, kp = (tid & 3) * 8;
  const int wm = wave * 16;
  floatx4 acc[3] = {};
  for (int k0 = 0; k0 < K; k0 += 32) {
    gl2lds16(A + (size_t)(bm + row0) * K + k0 + kp, lA + tid * 8);
    __syncthreads();
    bf16x8 af = *(const bf16x8*)&lA[(wm + r) * 32 + q * 8];
#pragma unroll
    for (int j = 0; j < 3; j++) {
      const bf16x8 bfr = *(const bf16x8*)&lW[(j * 16 + r) * K + k0 + q * 8];
      acc[j] = __builtin_amdgcn_mfma_f32_16x16x32_bf16(af, bfr, acc[j], 0, 0, 0);
    }
    __syncthreads();
  }
#pragma unroll
  for (int j = 0; j < 3; j++)
#pragma unroll
    for (int t = 0; t < 4; t++)
      out[(size_t)(bm + wm + q * 4 + t) * 48 + j * 16 + r] = acc[j][t];
}

// =================== scan pass1: per-chunk aggregates (dt fused + STORED; U bf16) ===================
// 2 adjacent e per thread; xc bulk-staged (dbuf); dbc[:,0:32] staged once;
// dt = softplus(dbc[:,0:16] . dtw[e] + bias) via packed-pair FMA, rounded to
// bf16 (consistent with pass3's replay), stored to dtout for pass3 to reuse.
__global__ __launch_bounds__(256) void scan_pass1(const bf16* __restrict__ xc,
                                                  const float* __restrict__ dbc,
                                                  const float* __restrict__ An,
                                                  const int* __restrict__ flags,
                                                  const float* __restrict__ dtw,
                                                  const float* __restrict__ dtb,
                                                  bf16* __restrict__ dtout,
                                                  bf16* __restrict__ U,
                                                  float* __restrict__ SD) {
  __shared__ __align__(16) float sbc[CL * 32];          // 4 KB: per pos dtr[16] B[16]
  __shared__ __align__(16) bf16 sxc_[2][SC * DI];       // 2 x 8 KB
  const int tid = threadIdx.x;
  const int e2 = tid * 2;
  const int ch = blockIdx.x, b = blockIdx.y;
  const size_t posBase = (size_t)b * SEQ + (size_t)ch * CL;
  {  // stage dbc cols 0..32 of CL rows: 256 chunks of 16B (all threads)
    const int il = tid >> 3, f = (tid & 7) * 4;
    gl2lds16(dbc + (posBase + il) * 48 + f, (char*)sbc + tid * 16);
  }
  stage_rows(xc + posBase * DI, sxc_[0], tid);
  const int2 fl = *(const int2*)(flags + e2);
  const int fast = fl.x & fl.y;
  f32x2 h[16];
#pragma unroll
  for (int s = 0; s < 16; s++) { h[s][0] = 0.f; h[s][1] = 0.f; }
  f32x2 sdt2; sdt2[0] = 0.f; sdt2[1] = 0.f;
  f32x2 A02; A02[0] = An[(size_t)e2 * 16]; A02[1] = An[(size_t)e2 * 16 + 16];
  // dt weights as packed pairs wp[r] = {dtw[e2][r], dtw[e2+1][r]}
  f32x2 wp[16];
#pragma unroll
  for (int r = 0; r < 16; r += 4) {
    float4 t0 = *(const float4*)(dtw + (size_t)e2 * 16 + r);
    float4 t1 = *(const float4*)(dtw + (size_t)(e2 + 1) * 16 + r);
    wp[r + 0][0] = t0.x; wp[r + 0][1] = t1.x;
    wp[r + 1][0] = t0.y; wp[r + 1][1] = t1.y;
    wp[r + 2][0] = t0.z; wp[r + 2][1] = t1.z;
    wp[r + 3][0] = t0.w; wp[r + 3][1] = t1.w;
  }
  const float2 bias = *(const float2*)(dtb + e2);
  __syncthreads();
  float2 dtc = rnd2(dt_pair(sbc, wp, bias));  // dt for step 0 (bf16-rounded)
#pragma unroll 1
  for (int sc = 0; sc < NSC; sc++) {
    const int cb = sc & 1;
    if (sc + 1 < NSC)
      stage_rows(xc + (posBase + (sc + 1) * SC) * DI, sxc_[cb ^ 1], tid);
    const char* sxcb = (const char*)sxc_[cb];
    const int tid4 = tid * 4;
    if (fast) {
#pragma unroll 2
      for (int il = 0; il < SC; il++) {
        const int ig = sc * SC + il;
        const int ng = (ig + 1 < CL) ? (ig + 1) : ig;
        const float2 dtn = rnd2(dt_pair(sbc + ng * 32, wp, bias));
        const unsigned ux = *(const unsigned*)(sxcb + il * 1024 + tid4);
        bf16x2 dto; dto[0] = (bf16)dtc.x; dto[1] = (bf16)dtc.y;
        *(bf16x2*)(dtout + (posBase + ig) * DI + e2) = dto;
        f32x2 dt2; dt2[0] = dtc.x; dt2[1] = dtc.y;
        f32x2 xv2; xv2[0] = bflo(ux); xv2[1] = bfhi(ux);
        const f32x2 dtx2 = dt2 * xv2;
        sdt2 = sdt2 + dt2;
        const f32x2 t = dt2 * A02;
        f32x2 d; d[0] = exp2_(t[0]); d[1] = exp2_(t[1]);
        f32x2 P[16];
        powseq(d, P);
        const float4* bb = (const float4*)(sbc + ig * 32 + 16);
#pragma unroll
        for (int g = 0; g < 4; g++) {
          const float4 B4 = bb[g];
          h[4 * g + 0] = P[4 * g + 0] * h[4 * g + 0] + dtx2 * sp2(B4.x);
          h[4 * g + 1] = P[4 * g + 1] * h[4 * g + 1] + dtx2 * sp2(B4.y);
          h[4 * g + 2] = P[4 * g + 2] * h[4 * g + 2] + dtx2 * sp2(B4.z);
          h[4 * g + 3] = P[4 * g + 3] * h[4 * g + 3] + dtx2 * sp2(B4.w);
        }
        dtc = dtn;
      }
    } else {
      // cold path (flags pattern broken): A read via volatile to avoid
      // register promotion; correctness identical.
      const volatile float* Ap = An + (size_t)e2 * 16;
      const volatile float* Bp = An + (size_t)e2 * 16 + 16;
#pragma unroll 1
      for (int il = 0; il < SC; il++) {
        const int ig = sc * SC + il;
        const int ng = (ig + 1 < CL) ? (ig + 1) : ig;
        const float2 dtn = rnd2(dt_pair(sbc + ng * 32, wp, bias));
        const unsigned ux = *(const unsigned*)(sxcb + il * 1024 + tid4);
        bf16x2 dto; dto[0] = (bf16)dtc.x; dto[1] = (bf16)dtc.y;
        *(bf16x2*)(dtout + (posBase + ig) * DI + e2) = dto;
        const float dta = dtc.x, dtb_v = dtc.y;
        const float xa = bflo(ux), xb = bfhi(ux);
        const float dtxa = dta * xa, dtxb = dtb_v * xb;
        sdt2[0] += dta; sdt2[1] += dtb_v;
        const float* bc = sbc + ig * 32 + 16;
#pragma unroll 1
        for (int s = 0; s < 16; s++) {
          const float bv = bc[s];
          h[s][0] = exp2_(dta * Ap[s]) * h[s][0] + dtxa * bv;
          h[s][1] = exp2_(dtb_v * Bp[s]) * h[s][1] + dtxb * bv;
        }
        dtc = dtn;
      }
    }
    __syncthreads();  // drain staging + protect buffer reuse
  }
  bf16* up = U + ((size_t)(b * NC + ch) * DI + e2) * 16;
  bf16x8 oa0, oa1, ob0, ob1;
#pragma unroll
  for (int i = 0; i < 8; i++) {
    oa0[i] = (bf16)h[i][0];
    oa1[i] = (bf16)h[8 + i][0];
    ob0[i] = (bf16)h[i][1];
    ob1[i] = (bf16)h[8 + i][1];
  }
  *(bf16x8*)(up) = oa0;
  *(bf16x8*)(up + 8) = oa1;
  *(bf16x8*)(up + 16) = ob0;
  *(bf16x8*)(up + 24) = ob1;
  float2 sdo; sdo.x = sdt2[0]; sdo.y = sdt2[1];
  *(float2*)(SD + (size_t)(b * NC + ch) * DI + e2) = sdo;
}

// =================== scan pass2: combine chunk aggregates (U bf16), parallel over (b,e,s) ===================
// group-of-16 pipelined loads; running h stays f32, stored h0 rounds to bf16.
__global__ __launch_bounds__(256) void scan_pass2(const float* __restrict__ SD,
                                                  bf16* U,
                                                  const float* __restrict__ An) {
  const int t = blockIdx.x * 256 + threadIdx.x;  // over BATCH*DI*16
  const int s = t & 15;
  const int e = (t >> 4) & (DI - 1);
  const int b = t >> 13;
  const float Av = An[e * 16 + s];  // pre-scaled by log2e
  const float* sdp = SD + (size_t)b * NC * DI + e;
  bf16* up = U + ((size_t)b * NC * DI + e) * 16 + s;
  float sA_[16], uA_[16], sB_[16], uB_[16];
#pragma unroll
  for (int j = 0; j < 16; j++) {
    sA_[j] = sdp[(size_t)j * DI];
    uA_[j] = (float)up[(size_t)j * DI * 16];
  }
  float h = 0.f;
#pragma unroll 1
  for (int c0 = 0; c0 < NC; c0 += 32) {
#pragma unroll
    for (int j = 0; j < 16; j++) {
      sB_[j] = sdp[(size_t)(c0 + 16 + j) * DI];
      uB_[j] = (float)up[(size_t)(c0 + 16 + j) * DI * 16];
    }
#pragma unroll
    for (int j = 0; j < 16; j++) {
      const float h0 = h;
      h = exp2_(Av * sA_[j]) * h0 + uA_[j];
      up[(size_t)(c0 + j) * DI * 16] = (bf16)h0;
    }
    const int nn = (c0 + 32 < NC) ? (c0 + 32) : (NC - 16);
#pragma unroll
    for (int j = 0; j < 16; j++) {
      sA_[j] = sdp[(size_t)(nn + j) * DI];
      uA_[j] = (float)up[(size_t)(nn + j) * DI * 16];
    }
#pragma unroll
    for (int j = 0; j < 16; j++) {
      const float h0 = h;
      h = exp2_(Av * sB_[j]) * h0 + uB_[j];
      up[(size_t)(c0 + 16 + j) * DI * 16] = (bf16)h0;
    }
  }
}

// =================== scan pass3: replay chunk from true h0 (bf16), emit gated y ===================
// 2 adjacent e per thread; software-pipelined global loads (prefetch il+1).
// dt read from pass1's stored buffer; slow-path A via volatile (VGPR trim).
__global__ __launch_bounds__(256) void scan_pass3(const bf16* __restrict__ dt,
                                                  const bf16* __restrict__ xc,
                                                  const bf16* __restrict__ xz,
                                                  const float* __restrict__ dbc,
                                                  const float* __restrict__ An,
                                                  const int* __restrict__ flags,
                                                  const bf16* __restrict__ H0,
                                                  const float* __restrict__ Dp,
                                                  bf16* __restrict__ yg) {
  __shared__ __align__(16) float sbc[CL * 32];  // per pos: B[16] C[16]
  const int tid = threadIdx.x;
  const int e2 = tid * 2;
  const int ch = blockIdx.x, b = blockIdx.y;
  const size_t posBase = (size_t)b * SEQ + (size_t)ch * CL;
  {
    const int il = tid >> 3, f = (tid & 7) * 4;
    gl2lds16(dbc + (posBase + il) * 48 + 16 + f, (char*)sbc + tid * 16);
  }
  const int2 fl = *(const int2*)(flags + e2);
  const int fast = fl.x & fl.y;
  f32x2 h[16];
  const bf16* hp = H0 + ((size_t)(b * NC + ch) * DI + e2) * 16;
  {
    const bf16x8 ha0 = *(const bf16x8*)(hp);
    const bf16x8 ha1 = *(const bf16x8*)(hp + 8);
    const bf16x8 hb0 = *(const bf16x8*)(hp + 16);
    const bf16x8 hb1 = *(const bf16x8*)(hp + 24);
#pragma unroll
    for (int i = 0; i < 8; i++) {
      h[i][0] = (float)ha0[i];
      h[8 + i][0] = (float)ha1[i];
      h[i][1] = (float)hb0[i];
      h[8 + i][1] = (float)hb1[i];
    }
  }
  const float2 Dv = *(const float2*)(Dp + e2);
  f32x2 Dv2; Dv2[0] = Dv.x; Dv2[1] = Dv.y;
  f32x2 A02; A02[0] = An[(size_t)e2 * 16]; A02[1] = An[(size_t)e2 * 16 + 16];
  // prefetch il=0
  const char* pdt = (const char*)(dt + posBase * DI + e2);
  const char* pxc = (const char*)(xc + posBase * DI + e2);
  const char* pxz = (const char*)(xz + posBase * 1024 + DI + e2);
  unsigned ud = *(const unsigned*)pdt;
  unsigned ux = *(const unsigned*)pxc;
  unsigned uz = *(const unsigned*)pxz;
  __syncthreads();
  if (fast) {
#pragma unroll 1
    for (int il = 0; il < CL; il++) {
      const int np = (il + 1 < CL) ? (il + 1) : il;
      const unsigned nud = *(const unsigned*)(pdt + (size_t)np * DI * 2);
      const unsigned nux = *(const unsigned*)(pxc + (size_t)np * DI * 2);
      const unsigned nuz = *(const unsigned*)(pxz + (size_t)np * 1024 * 2);
      const size_t pos = posBase + il;
      f32x2 dt2; dt2[0] = bflo(ud); dt2[1] = bfhi(ud);
      f32x2 xv2; xv2[0] = bflo(ux); xv2[1] = bfhi(ux);
      f32x2 z2; z2[0] = bflo(uz); z2[1] = bfhi(uz);
      const f32x2 dtx2 = dt2 * xv2;
      const f32x2 t = dt2 * A02;
      f32x2 d; d[0] = exp2_(t[0]); d[1] = exp2_(t[1]);
      f32x2 P[16];
      powseq(d, P);
      const float4* bb = (const float4*)(sbc + il * 32);
      f32x2 Yv[4];
#pragma unroll
      for (int g = 0; g < 4; g++) { Yv[g][0] = 0.f; Yv[g][1] = 0.f; }
#pragma unroll
      for (int g = 0; g < 4; g++) {
        const float4 B4 = bb[g];
        const float4 C4 = bb[4 + g];
        h[4 * g + 0] = P[4 * g + 0] * h[4 * g + 0] + dtx2 * sp2(B4.x);
        Yv[g] = Yv[g] + h[4 * g + 0] * sp2(C4.x);
        h[4 * g + 1] = P[4 * g + 1] * h[4 * g + 1] + dtx2 * sp2(B4.y);
        Yv[g] = Yv[g] + h[4 * g + 1] * sp2(C4.y);
        h[4 * g + 2] = P[4 * g + 2] * h[4 * g + 2] + dtx2 * sp2(B4.z);
        Yv[g] = Yv[g] + h[4 * g + 2] * sp2(C4.z);
        h[4 * g + 3] = P[4 * g + 3] * h[4 * g + 3] + dtx2 * sp2(B4.w);
        Yv[g] = Yv[g] + h[4 * g + 3] * sp2(C4.w);
      }
      const f32x2 Ys = (Yv[0] + Yv[1]) + (Yv[2] + Yv[3]);
      f32x2 gz; gz[0] = z2[0] * sigmoidf_(z2[0]); gz[1] = z2[1] * sigmoidf_(z2[1]);
      const f32x2 yv2 = (Ys + Dv2 * xv2) * gz;
      bf16x2 o; o[0] = (bf16)yv2[0]; o[1] = (bf16)yv2[1];
      *(bf16x2*)(yg + pos * DI + e2) = o;
      ud = nud; ux = nux; uz = nuz;
    }
  } else {
    // cold path: A via volatile (keeps 32 A-values out of static VGPR count)
    const volatile float* Ap = An + (size_t)e2 * 16;
    const volatile float* Bp = An + (size_t)e2 * 16 + 16;
#pragma unroll 1
    for (int il = 0; il < CL; il++) {
      const int np = (il + 1 < CL) ? (il + 1) : il;
      const unsigned nud = *(const unsigned*)(pdt + (size_t)np * DI * 2);
      const unsigned nux = *(const unsigned*)(pxc + (size_t)np * DI * 2);
      const unsigned nuz = *(const unsigned*)(pxz + (size_t)np * 1024 * 2);
      const size_t pos = posBase + il;
      const float dta = bflo(ud), dtb_v = bfhi(ud);
      const float xa = bflo(ux), xb = bfhi(ux);
      const float za = bflo(uz), zb = bfhi(uz);
      const float dtxa = dta * xa, dtxb = dtb_v * xb;
      const float* bc = sbc + il * 32;
      float ya = 0.f, yb = 0.f;
#pragma unroll 1
      for (int s = 0; s < 16; s++) {
        const float bv = bc[s], cv = bc[16 + s];
        const float ha = exp2_(dta * Ap[s]) * h[s][0] + dtxa * bv;
        const float hb = exp2_(dtb_v * Bp[s]) * h[s][1] + dtxb * bv;
        h[s][0] = ha; h[s][1] = hb;
        ya += ha * cv; yb += hb * cv;
      }
      const float yva = (ya + Dv.x * xa) * za * sigmoidf_(za);
      const float yvb = (yb + Dv.y * xb) * zb * sigmoidf_(zb);
      bf16x2 o; o[0] = (bf16)yva; o[1] = (bf16)yvb;
      *(bf16x2*)(yg + pos * DI + e2) = o;
      ud = nud; ux = nux; uz = nuz;
    }
  }
}

// =================== host ===================
extern "C" void kernel_launch(void* const* d_in, const int* in_sizes, int n_in,
                              void* d_out, int out_size, void* d_ws, size_t ws_size,
                              hipStream_t stream) {
  const float* x = (const float*)d_in[0];
  const float* ln_w = (const float*)d_in[1];
  const float* ln_b = (const float*)d_in[2];
  const float* w_in = (const float*)d_in[3];
  const float* conv_w = (const float*)d_in[4];
  const float* conv_b = (const float*)d_in[5];
  const float* w_x = (const float*)d_in[6];
  const float* w_dt = (const float*)d_in[7];
  const float* b_dt = (const float*)d_in[8];
  const float* a_log = (const float*)d_in[9];
  const float* d_par = (const float*)d_in[10];
  const float* w_out = (const float*)d_in[11];

  char* ws = (char*)d_ws;
  size_t off = 0;
  auto alloc = [&](size_t bytes) {
    void* p = ws + off;
    off = (off + bytes + 255) & ~(size_t)255;
    return p;
  };
  bf16* xzb = (bf16*)alloc((size_t)M * 1024 * 2);
  bf16* xcb = (bf16*)alloc((size_t)M * DI * 2);
  float* dbc = (float*)alloc((size_t)M * 48 * 4);
  bf16* dtb_ = (bf16*)alloc((size_t)M * DI * 2);
  bf16* ygb = (bf16*)alloc((size_t)M * DI * 2);
  bf16* U = (bf16*)alloc((size_t)BATCH * NC * DI * 16 * 2);  // 16.75 MB (bf16)
  bf16* xn = (bf16*)U;  // alias: xn (16MB) dead before U's first write (pass1 after gemm#1)
  float* SD = (float*)alloc((size_t)BATCH * NC * DI * 4);    // 2.1 MB
  bf16* w1b = (bf16*)alloc(1024 * 256 * 2);
  bf16* wxb = (bf16*)alloc(48 * 512 * 2);
  bf16* wob = (bf16*)alloc(256 * 512 * 2);
  float* An = (float*)alloc(512 * 16 * 4);
  int* flags = (int*)alloc(512 * 4);

  constexpr int prep_n = 1024 * 256 + 48 * 512 + 256 * 512 + DI;
  prep_kernel<<<dim3((prep_n + 255) / 256), dim3(256), 0, stream>>>(w_in, w_x, w_out, a_log, w1b, wxb, wob, An, flags);
  ln_kernel<<<dim3(M / 4), dim3(256), 0, stream>>>(x, ln_w, ln_b, xn);
  gemm_nt<1024, 256, true, false><<<dim3((M / 128) * 8), dim3(256), 0, stream>>>(xn, w1b, (void*)xzb, nullptr);
  conv_silu<<<dim3(SEQ / 8, BATCH), dim3(256), 0, stream>>>(xzb, conv_w, conv_b, xcb);
  gemm_xproj<<<dim3(M / 64), dim3(256), 0, stream>>>(xcb, wxb, dbc);
  scan_pass1<<<dim3(NC, BATCH), dim3(256), 0, stream>>>(xcb, dbc, An, flags, w_dt, b_dt, dtb_, U, SD);
  scan_pass2<<<dim3(BATCH * DI * 16 / 256), dim3(256), 0, stream>>>(SD, U, An);
  scan_pass3<<<dim3(NC, BATCH), dim3(256), 0, stream>>>(dtb_, xcb, xzb, dbc, An, flags, U, d_par, ygb);
  gemm_nt<256, 512, false, true><<<dim3((M / 128) * 2), dim3(256), 0, stream>>>(ygb, wob, d_out, x);
}